// Round 9
// baseline (4746.088 us; speedup 1.0000x reference)
//
#include <hip/hip_runtime.h>

typedef float  f32x4 __attribute__((ext_vector_type(4)));
typedef short  s16x8 __attribute__((ext_vector_type(8)));

__device__ __forceinline__ float b2f(short s) {
    return __uint_as_float(((unsigned)(unsigned short)s) << 16);
}
__device__ __forceinline__ short f2b(float f) {
    unsigned u = __float_as_uint(f);
    u = u + 0x7fffu + ((u >> 16) & 1u);
    return (short)(u >> 16);
}

// async global->LDS, 16B per lane; LDS dest = wave-uniform base + lane*16
__device__ __forceinline__ void gld_lds16(const short* g, short* l) {
    __builtin_amdgcn_global_load_lds(
        (const __attribute__((address_space(1))) unsigned int*)(const void*)g,
        (__attribute__((address_space(3))) unsigned int*)(void*)l,
        16, 0, 0);
}

// ---------------------------------------------------------------------------
// Reg-staged barrier-free bf16 GEMM (AITER-flatmm direction):
// C[M,N] = A[M,K]*Bt[N,K]^T (+bias). BM x 256 tile, 512 thr = 8 waves
// (2M x 4N), per-wave output BM/2 x 64, NO LDS, NO barriers.
// Each wave loads its MFMA fragments directly global->VGPR (dwordx4),
// double-buffered one BK=32 K-tile ahead; compiler emits counted vmcnt.
// Waves on a SIMD drift freely -> load/MFMA overlap across waves (m114).
// Fragment addressing = identical lane mapping to the LDS version:
//   A frag m: row m0+wm+m*16+(lane&15), cols t*32 + (lane>>4)*8
//   B frag n: row n0+wn+n*16+(lane&15), same cols.
// Per-tile block working set (A+B slices = 32KB) fits L1 -> the 4x A / 2x B
// fragment re-reads across waves are L1 hits; L2 sees compulsory traffic.
// epi: 0 Cb=bf16(v)  2 Cb=bf16(v+sym2[sid[row]]+pe[row&31])
//      3 Cb=bf16(relu v)  6 Cb=bf16(v+res[idx])
// ---------------------------------------------------------------------------
template<int BM>
__global__ __launch_bounds__(512) void gemm_reg(
    const short* __restrict__ A, const short* __restrict__ Bt,
    const float* __restrict__ bias,
    short* __restrict__ Cb,
    const short* __restrict__ res,
    const float* __restrict__ sym2, const int* __restrict__ sid,
    const float* __restrict__ pe,
    int M, int N, int K, int epi)
{
    constexpr int MF = BM / 32;            // m-frags per wave (8 or 4)

    const int tid  = threadIdx.x;
    const int lane = tid & 63;
    const int w    = tid >> 6;

    int bid = blockIdx.x;
    int nwg = gridDim.x;
    if ((nwg & 7) == 0) { int q = nwg >> 3; bid = (bid & 7) * q + (bid >> 3); }
    const int nbx = N >> 8;
    const int m0 = (bid / nbx) * BM;
    const int n0 = (bid % nbx) * 256;

    const int wm = (w >> 2) * (BM / 2);
    const int wn = (w & 3) * 64;
    const int l15 = lane & 15, l4 = lane >> 4;

    f32x4 acc[MF][4];
#pragma unroll
    for (int m = 0; m < MF; m++)
#pragma unroll
        for (int n = 0; n < 4; n++)
#pragma unroll
            for (int j = 0; j < 4; j++) acc[m][n][j] = 0.f;

    const short* aP[MF];
    const short* bP[4];
#pragma unroll
    for (int m = 0; m < MF; m++)
        aP[m] = A + (size_t)(m0 + wm + m * 16 + l15) * K + l4 * 8;
#pragma unroll
    for (int n = 0; n < 4; n++)
        bP[n] = Bt + (size_t)(n0 + wn + n * 16 + l15) * K + l4 * 8;

    s16x8 a0[MF], b0[4], a1[MF], b1[4];

    auto ld0 = [&](int t) {
        const int o = t * 32;
#pragma unroll
        for (int m = 0; m < MF; m++) a0[m] = *(const s16x8*)(aP[m] + o);
#pragma unroll
        for (int n = 0; n < 4; n++)  b0[n] = *(const s16x8*)(bP[n] + o);
    };
    auto ld1 = [&](int t) {
        const int o = t * 32;
#pragma unroll
        for (int m = 0; m < MF; m++) a1[m] = *(const s16x8*)(aP[m] + o);
#pragma unroll
        for (int n = 0; n < 4; n++)  b1[n] = *(const s16x8*)(bP[n] + o);
    };
    auto mm0 = [&]() {
#pragma unroll
        for (int m = 0; m < MF; m++)
#pragma unroll
            for (int n = 0; n < 4; n++)
                acc[m][n] = __builtin_amdgcn_mfma_f32_16x16x32_bf16(
                    a0[m], b0[n], acc[m][n], 0, 0, 0);
    };
    auto mm1 = [&]() {
#pragma unroll
        for (int m = 0; m < MF; m++)
#pragma unroll
            for (int n = 0; n < 4; n++)
                acc[m][n] = __builtin_amdgcn_mfma_f32_16x16x32_bf16(
                    a1[m], b1[n], acc[m][n], 0, 0, 0);
    };

    const int NT = K >> 5;          // BK=32 K-tiles; NT is even for all K here
    ld0(0);
    for (int t = 0; t < NT; t += 2) {
        if (t + 1 < NT) ld1(t + 1);     // issue next tile before consuming cur
        mm0();
        if (t + 2 < NT) ld0(t + 2);
        if (t + 1 < NT) mm1();
    }

    // ---- epilogue --------------------------------------------------------
#pragma unroll
    for (int m = 0; m < MF; m++) {
#pragma unroll
        for (int n = 0; n < 4; n++) {
#pragma unroll
            for (int j = 0; j < 4; j++) {
                int row = m0 + wm + m * 16 + l4 * 4 + j;
                int col = n0 + wn + n * 16 + l15;
                float v = acc[m][n][j];
                if (bias) v += bias[col];
                size_t idx = (size_t)row * N + col;
                if (epi == 0) {
                    Cb[idx] = f2b(v);
                } else if (epi == 2) {
                    v += sym2[(size_t)sid[row] * 1024 + col] + pe[(size_t)(row & 31) * 1024 + col];
                    Cb[idx] = f2b(v);
                } else if (epi == 3) {
                    Cb[idx] = f2b(fmaxf(v, 0.f));
                } else {
                    Cb[idx] = f2b(v + b2f(res[idx]));
                }
            }
        }
    }
}

// ---------------------------------------------------------------------------
// Small-M GEMM (M=128/256): 128x128 tile, 4 waves, gld_lds staging.
// epi: 0 Cb=bf16(v)  1 Cf=v  3 relu  5 Cf=v & Cb=bf16(v)  6 Cb=bf16(v+res)
// ---------------------------------------------------------------------------
__global__ __launch_bounds__(256) void gemm_bt(
    const short* __restrict__ A, const short* __restrict__ Bt,
    const float* __restrict__ bias,
    float* __restrict__ Cf, short* __restrict__ Cb,
    const short* __restrict__ res,
    int M, int N, int K, int epi)
{
    __shared__ short As[128 * 64];
    __shared__ short Bs[128 * 64];
    const int tid  = threadIdx.x;
    const int lane = tid & 63;
    const int wave = tid >> 6;
    const int m0 = blockIdx.y * 128, n0 = blockIdx.x * 128;
    const int wm = (wave >> 1) * 64, wn = (wave & 1) * 64;
    const int l15 = lane & 15, l4 = lane >> 4;

    f32x4 acc[4][4];
#pragma unroll
    for (int m = 0; m < 4; m++)
#pragma unroll
        for (int n = 0; n < 4; n++)
#pragma unroll
            for (int j = 0; j < 4; j++) acc[m][n][j] = 0.f;

    const int srow = wave * 32 + (lane >> 3);
    const int scol = (lane & 7) * 8;
    const short* Ag = A  + (size_t)(m0 + srow) * K + scol;
    const short* Bg = Bt + (size_t)(n0 + srow) * K + scol;
    short* Al = As + (wave * 32) * 64;
    short* Bl = Bs + (wave * 32) * 64;

    for (int k0 = 0; k0 < K; k0 += 64) {
#pragma unroll
        for (int i = 0; i < 4; i++) {
            gld_lds16(Ag + (size_t)(i * 8) * K + k0, Al + i * 8 * 64);
            gld_lds16(Bg + (size_t)(i * 8) * K + k0, Bl + i * 8 * 64);
        }
        __syncthreads();
#pragma unroll
        for (int kk = 0; kk < 64; kk += 32) {
            s16x8 af[4], bfv[4];
#pragma unroll
            for (int m = 0; m < 4; m++)
                af[m] = *(const s16x8*)(As + (wm + m * 16 + l15) * 64 + kk + l4 * 8);
#pragma unroll
            for (int n = 0; n < 4; n++)
                bfv[n] = *(const s16x8*)(Bs + (wn + n * 16 + l15) * 64 + kk + l4 * 8);
#pragma unroll
            for (int m = 0; m < 4; m++)
#pragma unroll
                for (int n = 0; n < 4; n++)
                    acc[m][n] = __builtin_amdgcn_mfma_f32_16x16x32_bf16(
                        af[m], bfv[n], acc[m][n], 0, 0, 0);
        }
        __syncthreads();
    }

#pragma unroll
    for (int m = 0; m < 4; m++) {
#pragma unroll
        for (int n = 0; n < 4; n++) {
#pragma unroll
            for (int j = 0; j < 4; j++) {
                int row = m0 + wm + m * 16 + l4 * 4 + j;
                int col = n0 + wn + n * 16 + l15;
                float v = acc[m][n][j];
                if (bias) v += bias[col];
                size_t idx = (size_t)row * N + col;
                if (epi == 0) {
                    Cb[idx] = f2b(v);
                } else if (epi == 1) {
                    Cf[idx] = v;
                } else if (epi == 3) {
                    Cb[idx] = f2b(fmaxf(v, 0.f));
                } else if (epi == 6) {
                    Cb[idx] = f2b(v + b2f(res[idx]));
                } else {
                    Cf[idx] = v; Cb[idx] = f2b(v);
                }
            }
        }
    }
}

// ---------------------------------------------------------------------------
// Self attention (layers 0,1): one block per (b,h). Tq=Tk=32, HD=128.
// ---------------------------------------------------------------------------
__global__ __launch_bounds__(256) void attn_self(const short* __restrict__ qkv,
                                                 short* __restrict__ o)
{
    const int b = blockIdx.x >> 3, h = blockIdx.x & 7;
    __shared__ short Q[32 * 128], Kk[32 * 128], Vv[32 * 128];
    __shared__ float S[32 * 32];
    const int tid = threadIdx.x;
    const size_t base = (size_t)b * 32 * 3072 + h * 128;
    for (int i = tid; i < 512; i += 256) {
        int r = i >> 4, c = (i & 15) * 8;
        size_t g = base + (size_t)r * 3072 + c;
        *(s16x8*)(Q  + r * 128 + c) = *(const s16x8*)(qkv + g);
        *(s16x8*)(Kk + r * 128 + c) = *(const s16x8*)(qkv + g + 1024);
        *(s16x8*)(Vv + r * 128 + c) = *(const s16x8*)(qkv + g + 2048);
    }
    __syncthreads();
    for (int i = tid; i < 1024; i += 256) {
        int r = i >> 5, c = i & 31;
        float s = 0.f;
        for (int d8 = 0; d8 < 16; d8++) {
            s16x8 qa = *(const s16x8*)(Q  + r * 128 + d8 * 8);
            s16x8 ka = *(const s16x8*)(Kk + c * 128 + d8 * 8);
#pragma unroll
            for (int j = 0; j < 8; j++) s += b2f(qa[j]) * b2f(ka[j]);
        }
        S[i] = s * 0.088388347648318447f;
    }
    __syncthreads();
    if (tid < 32) {
        float mx = -1e30f;
        for (int c = 0; c < 32; c++) mx = fmaxf(mx, S[tid * 32 + c]);
        float sum = 0.f;
        for (int c = 0; c < 32; c++) { float p = __expf(S[tid * 32 + c] - mx); S[tid * 32 + c] = p; sum += p; }
        float inv = 1.f / sum;
        for (int c = 0; c < 32; c++) S[tid * 32 + c] *= inv;
    }
    __syncthreads();
    for (int i = tid; i < 4096; i += 256) {
        int r = i >> 7, d = i & 127;
        float a = 0.f;
        for (int c = 0; c < 32; c++) a += S[r * 32 + c] * b2f(Vv[c * 128 + d]);
        o[(size_t)(b * 32 + r) * 1024 + h * 128 + d] = f2b(a);
    }
}

// Cross attention (layers 0,1): Tq=32, Tk=64, key-padding mask (1 = padded).
__global__ __launch_bounds__(256) void attn_cross(const short* __restrict__ q_,
                                                  const short* __restrict__ ckv,
                                                  const int* __restrict__ mask,
                                                  short* __restrict__ o)
{
    const int b = blockIdx.x >> 3, h = blockIdx.x & 7;
    __shared__ short Q[32 * 128], Kk[64 * 128], Vv[64 * 128];
    __shared__ float S[32 * 64];
    const int tid = threadIdx.x;
    for (int i = tid; i < 512; i += 256) {
        int r = i >> 4, c = (i & 15) * 8;
        *(s16x8*)(Q + r * 128 + c) = *(const s16x8*)(q_ + (size_t)(b * 32 + r) * 1024 + h * 128 + c);
    }
    for (int i = tid; i < 1024; i += 256) {
        int r = i >> 4, c = (i & 15) * 8;
        size_t g = (size_t)(b * 64 + r) * 2048 + h * 128 + c;
        *(s16x8*)(Kk + r * 128 + c) = *(const s16x8*)(ckv + g);
        *(s16x8*)(Vv + r * 128 + c) = *(const s16x8*)(ckv + g + 1024);
    }
    __syncthreads();
    for (int i = tid; i < 2048; i += 256) {
        int r = i >> 6, c = i & 63;
        float s = 0.f;
        for (int d8 = 0; d8 < 16; d8++) {
            s16x8 qa = *(const s16x8*)(Q  + r * 128 + d8 * 8);
            s16x8 ka = *(const s16x8*)(Kk + c * 128 + d8 * 8);
#pragma unroll
            for (int j = 0; j < 8; j++) s += b2f(qa[j]) * b2f(ka[j]);
        }
        s *= 0.088388347648318447f;
        if (mask[b * 64 + c] != 0) s = -1e9f;
        S[i] = s;
    }
    __syncthreads();
    if (tid < 32) {
        float mx = -1e30f;
        for (int c = 0; c < 64; c++) mx = fmaxf(mx, S[tid * 64 + c]);
        float sum = 0.f;
        for (int c = 0; c < 64; c++) { float p = __expf(S[tid * 64 + c] - mx); S[tid * 64 + c] = p; sum += p; }
        float inv = 1.f / sum;
        for (int c = 0; c < 64; c++) S[tid * 64 + c] *= inv;
    }
    __syncthreads();
    for (int i = tid; i < 4096; i += 256) {
        int r = i >> 7, d = i & 127;
        float a = 0.f;
        for (int c = 0; c < 64; c++) a += S[r * 64 + c] * b2f(Vv[c * 128 + d]);
        o[(size_t)(b * 32 + r) * 1024 + h * 128 + d] = f2b(a);
    }
}

// Last-position self attention (layer 3): 1 wave per (b,h).
__global__ __launch_bounds__(256) void attn_self_last(const short* __restrict__ q,
                                                      const short* __restrict__ kv,
                                                      short* __restrict__ out)
{
    __shared__ float qs[4][128];
    __shared__ float ps[4][32];
    const int wave = threadIdx.x >> 6, lane = threadIdx.x & 63;
    const int idx = blockIdx.x * 4 + wave;
    const int b = idx >> 3, h = idx & 7;
    for (int d = lane; d < 128; d += 64)
        qs[wave][d] = b2f(q[(size_t)b * 1024 + h * 128 + d]);
    __syncthreads();
    float s = -1e30f;
    if (lane < 32) {
        const short* kr = kv + (size_t)(b * 32 + lane) * 2048 + h * 128;
        float a = 0.f;
        for (int d = 0; d < 128; d += 8) {
            s16x8 kvv = *(const s16x8*)(kr + d);
#pragma unroll
            for (int j = 0; j < 8; j++) a += qs[wave][d + j] * b2f(kvv[j]);
        }
        s = a * 0.088388347648318447f;
    }
    float mx = s;
#pragma unroll
    for (int o = 1; o < 32; o <<= 1) mx = fmaxf(mx, __shfl_xor(mx, o));
    float p = (lane < 32) ? __expf(s - mx) : 0.f;
    float sum = p;
#pragma unroll
    for (int o = 1; o < 32; o <<= 1) sum += __shfl_xor(sum, o);
    if (lane < 32) ps[wave][lane] = p / sum;
    __syncthreads();
    for (int d = lane; d < 128; d += 64) {
        float a = 0.f;
        for (int j = 0; j < 32; j++)
            a += ps[wave][j] * b2f(kv[(size_t)(b * 32 + j) * 2048 + 1024 + h * 128 + d]);
        out[(size_t)b * 1024 + h * 128 + d] = f2b(a);
    }
}

// Last-position cross attention (layer 3): 1 wave per (b,h); 64 keys + mask.
__global__ __launch_bounds__(256) void attn_cross_last(const short* __restrict__ q,
                                                       const short* __restrict__ ckv,
                                                       const int* __restrict__ mask,
                                                       short* __restrict__ out)
{
    __shared__ float qs[4][128];
    __shared__ float ps[4][64];
    const int wave = threadIdx.x >> 6, lane = threadIdx.x & 63;
    const int idx = blockIdx.x * 4 + wave;
    const int b = idx >> 3, h = idx & 7;
    for (int d = lane; d < 128; d += 64)
        qs[wave][d] = b2f(q[(size_t)b * 1024 + h * 128 + d]);
    __syncthreads();
    const short* kr = ckv + (size_t)(b * 64 + lane) * 2048 + h * 128;
    float a = 0.f;
    for (int d = 0; d < 128; d += 8) {
        s16x8 kvv = *(const s16x8*)(kr + d);
#pragma unroll
        for (int j = 0; j < 8; j++) a += qs[wave][d + j] * b2f(kvv[j]);
    }
    float s = a * 0.088388347648318447f;
    if (mask[b * 64 + lane] != 0) s = -1e9f;
    float mx = s;
#pragma unroll
    for (int o = 1; o < 64; o <<= 1) mx = fmaxf(mx, __shfl_xor(mx, o));
    float p = __expf(s - mx);
    float sum = p;
#pragma unroll
    for (int o = 1; o < 64; o <<= 1) sum += __shfl_xor(sum, o);
    ps[wave][lane] = p / sum;
    __syncthreads();
    for (int d = lane; d < 128; d += 64) {
        float acc = 0.f;
        for (int j = 0; j < 64; j++)
            acc += ps[wave][j] * b2f(ckv[(size_t)(b * 64 + j) * 2048 + 1024 + h * 128 + d]);
        out[(size_t)b * 1024 + h * 128 + d] = f2b(acc);
    }
}

// Row LayerNorm over D=1024, bf16 in -> bf16 out. 128 thr/row (2 waves).
__global__ __launch_bounds__(128) void ln_rows_b(const short* __restrict__ X,
                                                 short* __restrict__ Y,
                                                 const float* __restrict__ g,
                                                 const float* __restrict__ bt)
{
    const int row = blockIdx.x, tid = threadIdx.x;
    s16x8 v = *(const s16x8*)(X + (size_t)row * 1024 + tid * 8);
    float f[8];
    float s = 0.f, q = 0.f;
#pragma unroll
    for (int j = 0; j < 8; j++) { f[j] = b2f(v[j]); s += f[j]; q += f[j] * f[j]; }
#pragma unroll
    for (int o = 1; o < 64; o <<= 1) { s += __shfl_xor(s, o); q += __shfl_xor(q, o); }
    __shared__ float ls[2], lq[2];
    if ((tid & 63) == 0) { ls[tid >> 6] = s; lq[tid >> 6] = q; }
    __syncthreads();
    s = ls[0] + ls[1];
    q = lq[0] + lq[1];
    const float mean = s * 0.0009765625f;
    const float var  = q * 0.0009765625f - mean * mean;
    const float rs = rsqrtf(var + 1e-5f);
    s16x8 ov;
#pragma unroll
    for (int j = 0; j < 8; j++) {
        int c = tid * 8 + j;
        ov[j] = f2b((f[j] - mean) * rs * g[c] + bt[c]);
    }
    *(s16x8*)(Y + (size_t)row * 1024 + tid * 8) = ov;
}

// f32 -> bf16 flat convert (n multiple of 8)
__global__ __launch_bounds__(256) void convf2b(const float* __restrict__ s,
                                               short* __restrict__ d, int n)
{
    int i = (blockIdx.x * 256 + threadIdx.x) * 8;
    if (i < n) {
        float4 a = *(const float4*)(s + i);
        float4 b = *(const float4*)(s + i + 4);
        s16x8 o;
        o[0] = f2b(a.x); o[1] = f2b(a.y); o[2] = f2b(a.z); o[3] = f2b(a.w);
        o[4] = f2b(b.x); o[5] = f2b(b.y); o[6] = f2b(b.z); o[7] = f2b(b.w);
        *(s16x8*)(d + i) = o;
    }
}

// batched f32 [R,C] -> bf16 [C,R] transpose-convert; blockIdx.z = matrix idx
__global__ __launch_bounds__(256) void transpose_conv_b(const float* __restrict__ src0,
                                                        short* __restrict__ dst0,
                                                        int R, int C)
{
    const float* src = src0 + (size_t)blockIdx.z * R * C;
    short* dst = dst0 + (size_t)blockIdx.z * R * C;
    __shared__ float t[32][33];
    int c0 = blockIdx.x * 32, r0 = blockIdx.y * 32;
    int tx = threadIdx.x & 31, ty = threadIdx.x >> 5;
#pragma unroll
    for (int i = 0; i < 32; i += 8) t[ty + i][tx] = src[(size_t)(r0 + ty + i) * C + c0 + tx];
    __syncthreads();
#pragma unroll
    for (int i = 0; i < 32; i += 8) dst[(size_t)(c0 + ty + i) * R + r0 + tx] = f2b(t[tx][ty + i]);
}

// pad rows to 128 (cols=1024), zero-fill beyond src_rows
__global__ __launch_bounds__(256) void pad_conv(const float* __restrict__ s,
                                                short* __restrict__ d, int src_rows)
{
    int i = blockIdx.x * 256 + threadIdx.x;
    int r = i >> 10;
    d[i] = (r < src_rows) ? f2b(s[i]) : (short)0;
}

// positional encoding table [32,1024]
__global__ __launch_bounds__(256) void pe_build(float* __restrict__ pe)
{
    int i = blockIdx.x * 256 + threadIdx.x;
    int t = i >> 10, d = i & 1023;
    int de = d & ~1;
    float ang = (float)t * expf((float)de * (-9.2103403719761836f / 1024.f));
    pe[i] = (d & 1) ? cosf(ang) : sinf(ang);
}

// gather last decode position: xlast[b] = x[b*32+31]
__global__ __launch_bounds__(256) void gather_last(const short* __restrict__ x,
                                                   short* __restrict__ xlast)
{
    int i = blockIdx.x * 256 + threadIdx.x;
    int b = i >> 10, d = i & 1023;
    xlast[i] = x[((size_t)(b * 32 + 31) << 10) + d];
}

// Final routed heads -> nll[b]. One wave per batch element.
__global__ __launch_bounds__(64) void head_final(
    const float* __restrict__ logits_a,
    const float* __restrict__ enc_col_f, const short* __restrict__ yc,
    const float* __restrict__ enc_tab_f, const short* __restrict__ yt,
    const float* __restrict__ outf,
    const float* __restrict__ col_b, const float* __restrict__ tab_b,
    const int* __restrict__ view, const int* __restrict__ ga,
    const int* __restrict__ gc, const int* __restrict__ gt,
    float* __restrict__ nll)
{
    const int b = blockIdx.x, lane = threadIdx.x;
    const int vt = view[b];
    if (vt == 0) {
        float x = logits_a[(size_t)b * 128 + lane];
        float mx = x;
#pragma unroll
        for (int o = 1; o < 64; o <<= 1) mx = fmaxf(mx, __shfl_xor(mx, o));
        float sum = __expf(x - mx);
#pragma unroll
        for (int o = 1; o < 64; o <<= 1) sum += __shfl_xor(sum, o);
        float lse = mx + logf(sum);
        float gl = __shfl(x, ga[b]);
        if (lane == 0) nll[b] = lse - gl;
    } else {
        const int nit = (vt == 1) ? 32 : 16;
        const float* enc = (vt == 1) ? (enc_col_f + (size_t)b * 32 * 1024)
                                     : (enc_tab_f + (size_t)b * 16 * 1024);
        const short* y   = (vt == 1) ? (yc + (size_t)b * 1024) : (yt + (size_t)b * 1024);
        const float* bb  = (vt == 1) ? col_b : tab_b;
        float bc = 0.f;
        for (int i = lane; i < 1024; i += 64) bc += bb[i] * outf[(size_t)b * 1024 + i];
#pragma unroll
        for (int o = 1; o < 64; o <<= 1) bc += __shfl_xor(bc, o);
        float logit = -1e30f;
        if (lane < nit) {
            float s = bc;
            const float* er = enc + (size_t)lane * 1024;
            for (int d8 = 0; d8 < 128; d8++) {
                s16x8 yv = *(const s16x8*)(y + d8 * 8);
                float4 e0 = *(const float4*)(er + d8 * 8);
                float4 e1 = *(const float4*)(er + d8 * 8 + 4);
                s += e0.x * b2f(yv[0]) + e0.y * b2f(yv[1]) + e0.z * b2f(yv[2]) + e0.w * b2f(yv[3])
                   + e1.x * b2f(yv[4]) + e1.y * b2f(yv[5]) + e1.z * b2f(yv[6]) + e1.w * b2f(yv[7]);
            }
            logit = s;
        }
        float mx = logit;
#pragma unroll
        for (int o = 1; o < 64; o <<= 1) mx = fmaxf(mx, __shfl_xor(mx, o));
        float sum = (lane < nit) ? __expf(logit - mx) : 0.f;
#pragma unroll
        for (int o = 1; o < 64; o <<= 1) sum += __shfl_xor(sum, o);
        float lse = mx + logf(sum);
        int g = (vt == 1) ? gc[b] : gt[b];
        float gl = __shfl(logit, g);
        if (lane == 0) nll[b] = lse - gl;
    }
}

// ---------------------------------------------------------------------------
extern "C" void kernel_launch(void* const* d_in, const int* in_sizes, int n_in,
                              void* d_out, int out_size, void* d_ws, size_t ws_size,
                              hipStream_t stream)
{
    const float* pa_f     = (const float*)d_in[0];
    const float* src_f    = (const float*)d_in[1];
    const float* colenc_f = (const float*)d_in[2];
    const float* tabenc_f = (const float*)d_in[3];
    const int*   src_mask = (const int*)d_in[4];
    const int*   sym_ids  = (const int*)d_in[5];
    const int*   view     = (const int*)d_in[6];
    const int*   gold_a   = (const int*)d_in[7];
    const int*   gold_c   = (const int*)d_in[8];
    const int*   gold_t   = (const int*)d_in[9];
    const float* sym_emb  = (const float*)d_in[10];
    const float* act_emb  = (const float*)d_in[11];
    const float* Aaff_w   = (const float*)d_in[12];
    const float* Aaff_b   = (const float*)d_in[13];
    const float* Saff_w   = (const float*)d_in[14];
    const float* Saff_b   = (const float*)d_in[15];
    const float* Caff_w   = (const float*)d_in[16];
    const float* Caff_b   = (const float*)d_in[17];
    const float* Taff_w   = (const float*)d_in[18];
    const float* Taff_b   = (const float*)d_in[19];
    const float* tgt_w    = (const float*)d_in[20];
    const float* tgt_b    = (const float*)d_in[21];
    const float* outw     = (const float*)d_in[22];
    const float* outbias  = (const float*)d_in[23];
    const float* self_w   = (const float*)d_in[24];
    const float* self_b   = (const float*)d_in[25];
    const float* cross_w  = (const float*)d_in[26];
    const float* cross_b  = (const float*)d_in[27];
    const float* f1w      = (const float*)d_in[28];
    const float* f1b      = (const float*)d_in[29];
    const float* f2w      = (const float*)d_in[30];
    const float* f2bb     = (const float*)d_in[31];
    const float* lng      = (const float*)d_in[32];
    const float* lnbt     = (const float*)d_in[33];
    float* nll = (float*)d_out;

    char* ws = (char*)d_ws;
    size_t off = 0;
    auto alloc = [&](size_t bytes) -> char* {
        off = (off + 255) & ~(size_t)255;
        char* p = ws + off; off += bytes; return p;
    };

    const size_t MB1 = (size_t)1024 * 1024;
    short* WAaff  = (short*)alloc(MB1 * 2);
    short* WSaff  = (short*)alloc(MB1 * 2);
    short* Wtop   = (short*)alloc(MB1 * 2);
    short* Wbot   = (short*)alloc(MB1 * 2);
    short* Wout   = (short*)alloc(MB1 * 2);
    short* Wcol   = (short*)alloc(MB1 * 2);
    short* Wtab   = (short*)alloc(MB1 * 2);
    short* Wself  = (short*)alloc(12 * MB1 * 2);
    short* Wcross = (short*)alloc(12 * MB1 * 2);
    short* Wf1a   = (short*)alloc(3 * 2 * MB1 * 2);
    short* Wf2a   = (short*)alloc(3 * 2 * MB1 * 2);

    short* src_bf   = (short*)alloc((size_t)16384 * 1024 * 2);
    short* sym_pad  = (short*)alloc((size_t)128 * 1024 * 2);
    short* act_pad  = (short*)alloc((size_t)128 * 1024 * 2);
    short* sa_out   = (short*)alloc((size_t)128 * 1024 * 2);
    float* sym2     = (float*)alloc((size_t)128 * 1024 * 4);
    float* pe       = (float*)alloc((size_t)32 * 1024 * 4);
    short* tgt_a    = (short*)alloc((size_t)8192 * 1024 * 2);
    short* x_bf     = (short*)alloc((size_t)8192 * 1024 * 2);
    short* tmpb     = (short*)alloc((size_t)8192 * 1024 * 2);
    short* arena    = (short*)alloc((size_t)16384 * 2048 * 2);
    short* xlast    = (short*)alloc((size_t)256 * 1024 * 2);
    float* outf     = (float*)alloc((size_t)256 * 1024 * 4);
    short* outb16   = (short*)alloc((size_t)256 * 1024 * 2);
    short* srca     = (short*)alloc((size_t)128 * 1024 * 2);
    float* logits_a = (float*)alloc((size_t)256 * 128 * 4);
    short* ycb      = (short*)alloc((size_t)256 * 1024 * 2);
    short* ytb      = (short*)alloc((size_t)256 * 1024 * 2);
    short* xq31     = (short*)alloc((size_t)256 * 1024 * 2);
    short* x256a    = (short*)alloc((size_t)256 * 1024 * 2);
    short* x256b    = (short*)alloc((size_t)256 * 1024 * 2);
    short* q256     = (short*)alloc((size_t)256 * 1024 * 2);
    short* cq256    = (short*)alloc((size_t)256 * 1024 * 2);
    short* o256     = (short*)alloc((size_t)256 * 1024 * 2);
    short* h256     = (short*)alloc((size_t)256 * 2048 * 2);
    short* tmpb256  = (short*)alloc((size_t)256 * 1024 * 2);

    short* pa_bf = tmpb;   // alias: dead before tmpb first written
    short* cq    = tmpb;   // alias: live only between LN1 and cross attn
    short* attn  = tgt_a;  // alias: tgt_a dead once x is built

    const dim3 BLK(256);
    auto conv = [&](const float* s, short* d, size_t n) {
        convf2b<<<dim3((unsigned)(n / 8 / 256)), BLK, 0, stream>>>(s, d, (int)n);
    };
    auto trans = [&](const float* s, short* d, int R, int C, int nm) {
        transpose_conv_b<<<dim3(C / 32, R / 32, nm), BLK, 0, stream>>>(s, d, R, C);
    };
    auto gp = [&](const short* A, const short* Bt, const float* bias,
                  short* Cb, const short* res,
                  const float* sy, const int* si, const float* pp,
                  int M, int N, int K, int epi, int BM) {
        if (BM == 256)
            gemm_reg<256><<<dim3((N / 256) * (M / 256)), dim3(512), 0, stream>>>(
                A, Bt, bias, Cb, res, sy, si, pp, M, N, K, epi);
        else
            gemm_reg<128><<<dim3((N / 256) * (M / 128)), dim3(512), 0, stream>>>(
                A, Bt, bias, Cb, res, sy, si, pp, M, N, K, epi);
    };
    auto gsm = [&](const short* A, const short* Bt, const float* bias,
                   float* Cf, short* Cb, const short* res,
                   int M, int N, int K, int epi) {
        gemm_bt<<<dim3(N / 128, M / 128), BLK, 0, stream>>>(
            A, Bt, bias, Cf, Cb, res, M, N, K, epi);
    };

    // ---- phase 0: conversions (batched) ----------------------------------
    pe_build<<<dim3(128), BLK, 0, stream>>>(pe);
    conv(pa_f, pa_bf, (size_t)8192 * 1024);
    conv(src_f, src_bf, (size_t)16384 * 1024);
    conv(Caff_w, Wcol, MB1);
    conv(Taff_w, Wtab, MB1);
    pad_conv<<<dim3(512), BLK, 0, stream>>>(sym_emb, sym_pad, 32);
    pad_conv<<<dim3(512), BLK, 0, stream>>>(act_emb, act_pad, 64);
    trans(Aaff_w, WAaff, 1024, 1024, 1);
    trans(Saff_w, WSaff, 1024, 1024, 1);
    trans(tgt_w, Wtop, 1024, 1024, 1);
    trans(tgt_w + MB1, Wbot, 1024, 1024, 1);
    trans(outw, Wout, 1024, 1024, 1);
    trans(self_w, Wself, 1024, 1024, 12);
    trans(cross_w, Wcross, 1024, 1024, 12);
    trans(f1w, Wf1a, 1024, 2048, 3);
    trans(f2w, Wf2a, 2048, 1024, 3);

    // ---- phase 1: embeddings --------------------------------------------
    gsm(sym_pad, WSaff, Saff_b, nullptr, sa_out, nullptr, 128, 1024, 1024, 0);
    gsm(sa_out, Wbot, nullptr, sym2, nullptr, nullptr, 128, 1024, 1024, 1);
    gp(pa_bf, WAaff, Aaff_b, tgt_a, nullptr, nullptr, nullptr, nullptr,
       8192, 1024, 1024, 0, 128);
    gp(tgt_a, Wtop, tgt_b, x_bf, nullptr, sym2, sym_ids, pe,
       8192, 1024, 1024, 2, 128);

    // ---- phase 2: decoder layers 0,1 (full) ------------------------------
    for (int l = 0; l < 2; l++) {
        const float* sb = self_b + (size_t)l * 4096;
        const float* cb = cross_b + (size_t)l * 4096;
        gp(x_bf, Wself + (size_t)(4 * l) * MB1, sb, arena, nullptr, nullptr, nullptr, nullptr,
           8192, 3072, 1024, 0, 256);
        attn_self<<<dim3(2048), BLK, 0, stream>>>(arena, attn);
        gp(attn, Wself + (size_t)(4 * l + 3) * MB1, sb + 3072, tmpb, x_bf, nullptr, nullptr, nullptr,
           8192, 1024, 1024, 6, 128);
        ln_rows_b<<<dim3(8192), dim3(128), 0, stream>>>(tmpb, x_bf,
            lng + (size_t)(l * 3 + 0) * 1024, lnbt + (size_t)(l * 3 + 0) * 1024);
        gp(x_bf, Wcross + (size_t)(4 * l) * MB1, cb, cq, nullptr, nullptr, nullptr, nullptr,
           8192, 1024, 1024, 0, 128);
        gp(src_bf, Wcross + (size_t)(4 * l + 1) * MB1, cb + 1024, arena, nullptr, nullptr, nullptr, nullptr,
           16384, 2048, 1024, 0, 256);
        attn_cross<<<dim3(2048), BLK, 0, stream>>>(cq, arena, src_mask, attn);
        gp(attn, Wcross + (size_t)(4 * l + 3) * MB1, cb + 3072, tmpb, x_bf, nullptr, nullptr, nullptr,
           8192, 1024, 1024, 6, 128);
        ln_rows_b<<<dim3(8192), dim3(128), 0, stream>>>(tmpb, x_bf,
            lng + (size_t)(l * 3 + 1) * 1024, lnbt + (size_t)(l * 3 + 1) * 1024);
        gp(x_bf, Wf1a + (size_t)l * 2 * MB1, f1b + (size_t)l * 2048, arena, nullptr, nullptr, nullptr, nullptr,
           8192, 2048, 1024, 3, 256);
        gp(arena, Wf2a + (size_t)l * 2 * MB1, f2bb + (size_t)l * 1024, tmpb, x_bf, nullptr, nullptr, nullptr,
           8192, 1024, 2048, 6, 128);
        ln_rows_b<<<dim3(8192), dim3(128), 0, stream>>>(tmpb, x_bf,
            lng + (size_t)(l * 3 + 2) * 1024, lnbt + (size_t)(l * 3 + 2) * 1024);
    }

    // ---- layer 2: only last position matters downstream ------------------
    {
        const float* sb = self_b + (size_t)2 * 4096;
        const float* cb = cross_b + (size_t)2 * 4096;
        gather_last<<<dim3(1024), BLK, 0, stream>>>(x_bf, xq31);
        gp(x_bf, Wself + (size_t)(4 * 2 + 1) * MB1, sb + 1024, arena, nullptr, nullptr, nullptr, nullptr,
           8192, 2048, 1024, 0, 256);   // K,V all positions
        gsm(xq31, Wself + (size_t)(4 * 2) * MB1, sb, nullptr, q256, nullptr, 256, 1024, 1024, 0);
        attn_self_last<<<dim3(512), BLK, 0, stream>>>(q256, arena, o256);
        gsm(o256, Wself + (size_t)(4 * 2 + 3) * MB1, sb + 3072, nullptr, tmpb256, xq31, 256, 1024, 1024, 6);
        ln_rows_b<<<dim3(256), dim3(128), 0, stream>>>(tmpb256, x256a,
            lng + (size_t)(2 * 3 + 0) * 1024, lnbt + (size_t)(2 * 3 + 0) * 1024);
        gsm(x256a, Wcross + (size_t)(4 * 2) * MB1, cb, nullptr, cq256, nullptr, 256, 1024, 1024, 0);
        gp(src_bf, Wcross + (size_t)(4 * 2 + 1) * MB1, cb + 1024, arena, nullptr, nullptr, nullptr, nullptr,
           16384, 2048, 1024, 0, 256);
        attn_cross_last<<<dim3(512), BLK, 0, stream>>>(cq256, arena, src_mask, o256);
        gsm(o256, Wcross + (size_t)(4 * 2 + 3) * MB1, cb + 3072, nullptr, tmpb256, x256a, 256, 1024, 1024, 6);
        ln_rows_b<<<dim3(256), dim3(128), 0, stream>>>(tmpb256, x256b,
            lng + (size_t)(2 * 3 + 1) * 1024, lnbt + (size_t)(2 * 3 + 1) * 1024);
        gsm(x256b, Wf1a + (size_t)2 * 2 * MB1, f1b + (size_t)2 * 2048, nullptr, h256, nullptr,
            256, 2048, 1024, 3);
        gsm(h256, Wf2a + (size_t)2 * 2 * MB1, f2bb + (size_t)2 * 1024, nullptr, tmpb256, x256b,
            256, 1024, 2048, 6);
        ln_rows_b<<<dim3(256), dim3(128), 0, stream>>>(tmpb256, xlast,
            lng + (size_t)(2 * 3 + 2) * 1024, lnbt + (size_t)(2 * 3 + 2) * 1024);
    }

    // ---- phase 3: heads --------------------------------------------------
    gsm(xlast, Wout, outbias, outf, outb16, nullptr, 256, 1024, 1024, 5);
    gsm(act_pad, WAaff, Aaff_b, nullptr, srca, nullptr, 128, 1024, 1024, 0);
    gsm(outb16, srca, nullptr, logits_a, nullptr, nullptr, 256, 128, 1024, 1);
    gsm(outb16, Wcol, nullptr, nullptr, ycb, nullptr, 256, 1024, 1024, 0);
    gsm(outb16, Wtab, nullptr, nullptr, ytb, nullptr, 256, 1024, 1024, 0);
    head_final<<<dim3(256), dim3(64), 0, stream>>>(
        logits_a, colenc_f, ycb, tabenc_f, ytb, outf,
        Caff_b, Taff_b, view, gold_a, gold_c, gold_t, nll);
}

// Round 10
// 2534.655 us; speedup vs baseline: 1.8725x; 1.8725x over previous
//
#include <hip/hip_runtime.h>

typedef float  f32x4 __attribute__((ext_vector_type(4)));
typedef short  s16x8 __attribute__((ext_vector_type(8)));

__device__ __forceinline__ float b2f(short s) {
    return __uint_as_float(((unsigned)(unsigned short)s) << 16);
}
__device__ __forceinline__ short f2b(float f) {
    unsigned u = __float_as_uint(f);
    u = u + 0x7fffu + ((u >> 16) & 1u);
    return (short)(u >> 16);
}

// async global->LDS, 16B per lane; LDS dest = wave-uniform base + lane*16
__device__ __forceinline__ void gld_lds16(const short* g, short* l) {
    __builtin_amdgcn_global_load_lds(
        (const __attribute__((address_space(1))) unsigned int*)(const void*)g,
        (__attribute__((address_space(3))) unsigned int*)(void*)l,
        16, 0, 0);
}

#define S_VMCNT0    asm volatile("s_waitcnt vmcnt(0)" ::: "memory")
#define S_LGKM0     asm volatile("s_waitcnt lgkmcnt(0)" ::: "memory")
#define SBAR        __builtin_amdgcn_s_barrier()
#define SCHED0      __builtin_amdgcn_sched_barrier(0)

// ---------------------------------------------------------------------------
// 2-phase pipelined bf16 GEMM (round-5 best: 163-165us on ckv):
// C[M,N] = A[M,K]*Bt[N,K]^T (+bias). BM x 256 tile, BK=64, 512 thr = 8 waves
// (2M x 4N). Per K-tile: stage(t+1 -> other buf), 2 halves of
// {ds_read -> lgkm0 -> setprio MFMA(32)}, vmcnt(0) -> s_barrier.
// LDS swizzle (row 128B = 8x16B chunks): slot c of row r holds global chunk
// c^(r&7); stage src chunk (lane&7)^(lane>>3); read chunk l4^(lane&7),
// kstep1 = byte ^64. Measured 0 bank conflicts.
// epi: 0 Cb=bf16(v)  2 Cb=bf16(v+sym2[sid[row]]+pe[row&31])
//      3 Cb=bf16(relu v)  6 Cb=bf16(v+res[idx])
// ---------------------------------------------------------------------------
template<int BM>
__global__ __launch_bounds__(512) void gemm_pipe(
    const short* __restrict__ A, const short* __restrict__ Bt,
    const float* __restrict__ bias,
    short* __restrict__ Cb,
    const short* __restrict__ res,
    const float* __restrict__ sym2, const int* __restrict__ sid,
    const float* __restrict__ pe,
    int M, int N, int K, int epi)
{
    constexpr int MF   = BM / 32;
    constexpr int ALW  = BM / 64;
    constexpr int BUFB = (BM + 256) * 128;
    __shared__ short lds[2 * (BM + 256) * 64];

    const int tid  = threadIdx.x;
    const int lane = tid & 63;
    const int wave = tid >> 6;

    int bid = blockIdx.x;
    int nwg = gridDim.x;
    if ((nwg & 7) == 0) { int q = nwg >> 3; bid = (bid & 7) * q + (bid >> 3); }
    const int nbx = N >> 8;
    const int m0 = (bid / nbx) * BM;
    const int n0 = (bid % nbx) * 256;

    const int wm = (wave >> 2) * (BM / 2);
    const int wn = (wave & 3) * 64;
    const int l15 = lane & 15, l4 = lane >> 4;
    const int key = lane & 7;

    f32x4 acc[MF][4];
#pragma unroll
    for (int m = 0; m < MF; m++)
#pragma unroll
        for (int n = 0; n < 4; n++)
#pragma unroll
            for (int j = 0; j < 4; j++) acc[m][n][j] = 0.f;

    int aoff[MF], boff[4];
#pragma unroll
    for (int m = 0; m < MF; m++) {
        int r = wm + m * 16 + l15;
        aoff[m] = r * 128 + ((l4 ^ key) << 4);
    }
#pragma unroll
    for (int n = 0; n < 4; n++) {
        int r = wn + n * 16 + l15;
        boff[n] = BM * 128 + r * 128 + ((l4 ^ key) << 4);
    }

    const int lrow = lane >> 3;
    const int lchunk = (lane & 7) ^ lrow;
    size_t agoff[ALW]; int aldo[ALW];
#pragma unroll
    for (int i = 0; i < ALW; i++) {
        int rr = wave * (BM / 8) + i * 8;
        agoff[i] = (size_t)(m0 + rr + lrow) * K + lchunk * 8;
        aldo[i]  = rr * 128;
    }
    size_t bgoff[4]; int bldo[4];
#pragma unroll
    for (int i = 0; i < 4; i++) {
        int rr = wave * 32 + i * 8;
        bgoff[i] = (size_t)(n0 + rr + lrow) * K + lchunk * 8;
        bldo[i]  = BM * 128 + rr * 128;
    }

    char* lbase = (char*)lds;
    auto stage = [&](int kt, int bufoff) {
        char* lb = lbase + bufoff;
        const size_t ke = (size_t)kt * 64;
#pragma unroll
        for (int i = 0; i < ALW; i++)
            gld_lds16(A + agoff[i] + ke, (short*)(lb + aldo[i]));
#pragma unroll
        for (int i = 0; i < 4; i++)
            gld_lds16(Bt + bgoff[i] + ke, (short*)(lb + bldo[i]));
    };

    const int NT = K >> 6;
    stage(0, 0);
    S_VMCNT0; SCHED0; SBAR; SCHED0;

    int cb = 0;
    for (int t = 0; t < NT; t++) {
        if (t + 1 < NT) stage(t + 1, (cb ^ 1) * BUFB);
        const char* cp = lbase + cb * BUFB;
        {
            s16x8 af[MF], bv[4];
#pragma unroll
            for (int m = 0; m < MF; m++) af[m] = *(const s16x8*)(cp + aoff[m]);
#pragma unroll
            for (int n = 0; n < 4; n++)  bv[n] = *(const s16x8*)(cp + boff[n]);
            S_LGKM0; SCHED0;
            __builtin_amdgcn_s_setprio(1);
#pragma unroll
            for (int m = 0; m < MF; m++)
#pragma unroll
                for (int n = 0; n < 4; n++)
                    acc[m][n] = __builtin_amdgcn_mfma_f32_16x16x32_bf16(
                        af[m], bv[n], acc[m][n], 0, 0, 0);
            __builtin_amdgcn_s_setprio(0);
        }
        {
            s16x8 af[MF], bv[4];
#pragma unroll
            for (int m = 0; m < MF; m++) af[m] = *(const s16x8*)(cp + (aoff[m] ^ 64));
#pragma unroll
            for (int n = 0; n < 4; n++)  bv[n] = *(const s16x8*)(cp + (boff[n] ^ 64));
            S_LGKM0; SCHED0;
            __builtin_amdgcn_s_setprio(1);
#pragma unroll
            for (int m = 0; m < MF; m++)
#pragma unroll
                for (int n = 0; n < 4; n++)
                    acc[m][n] = __builtin_amdgcn_mfma_f32_16x16x32_bf16(
                        af[m], bv[n], acc[m][n], 0, 0, 0);
            __builtin_amdgcn_s_setprio(0);
        }
        S_VMCNT0; SCHED0; SBAR; SCHED0;
        cb ^= 1;
    }

#pragma unroll
    for (int m = 0; m < MF; m++) {
#pragma unroll
        for (int n = 0; n < 4; n++) {
#pragma unroll
            for (int j = 0; j < 4; j++) {
                int row = m0 + wm + m * 16 + l4 * 4 + j;
                int col = n0 + wn + n * 16 + l15;
                float v = acc[m][n][j];
                if (bias) v += bias[col];
                size_t idx = (size_t)row * N + col;
                if (epi == 0) {
                    Cb[idx] = f2b(v);
                } else if (epi == 2) {
                    v += sym2[(size_t)sid[row] * 1024 + col] + pe[(size_t)(row & 31) * 1024 + col];
                    Cb[idx] = f2b(v);
                } else if (epi == 3) {
                    Cb[idx] = f2b(fmaxf(v, 0.f));
                } else {
                    Cb[idx] = f2b(v + b2f(res[idx]));
                }
            }
        }
    }
}

// ---------------------------------------------------------------------------
// Small-M GEMM (M=128..1024): 128x128 tile, 4 waves, gld_lds staging.
// epi: 0 Cb=bf16(v)  1 Cf=v  3 relu  5 Cf=v & Cb=bf16(v)  6 Cb=bf16(v+res)
// ---------------------------------------------------------------------------
__global__ __launch_bounds__(256) void gemm_bt(
    const short* __restrict__ A, const short* __restrict__ Bt,
    const float* __restrict__ bias,
    float* __restrict__ Cf, short* __restrict__ Cb,
    const short* __restrict__ res,
    int M, int N, int K, int epi)
{
    __shared__ short As[128 * 64];
    __shared__ short Bs[128 * 64];
    const int tid  = threadIdx.x;
    const int lane = tid & 63;
    const int wave = tid >> 6;
    const int m0 = blockIdx.y * 128, n0 = blockIdx.x * 128;
    const int wm = (wave >> 1) * 64, wn = (wave & 1) * 64;
    const int l15 = lane & 15, l4 = lane >> 4;

    f32x4 acc[4][4];
#pragma unroll
    for (int m = 0; m < 4; m++)
#pragma unroll
        for (int n = 0; n < 4; n++)
#pragma unroll
            for (int j = 0; j < 4; j++) acc[m][n][j] = 0.f;

    const int srow = wave * 32 + (lane >> 3);
    const int scol = (lane & 7) * 8;
    const short* Ag = A  + (size_t)(m0 + srow) * K + scol;
    const short* Bg = Bt + (size_t)(n0 + srow) * K + scol;
    short* Al = As + (wave * 32) * 64;
    short* Bl = Bs + (wave * 32) * 64;

    for (int k0 = 0; k0 < K; k0 += 64) {
#pragma unroll
        for (int i = 0; i < 4; i++) {
            gld_lds16(Ag + (size_t)(i * 8) * K + k0, Al + i * 8 * 64);
            gld_lds16(Bg + (size_t)(i * 8) * K + k0, Bl + i * 8 * 64);
        }
        __syncthreads();
#pragma unroll
        for (int kk = 0; kk < 64; kk += 32) {
            s16x8 af[4], bfv[4];
#pragma unroll
            for (int m = 0; m < 4; m++)
                af[m] = *(const s16x8*)(As + (wm + m * 16 + l15) * 64 + kk + l4 * 8);
#pragma unroll
            for (int n = 0; n < 4; n++)
                bfv[n] = *(const s16x8*)(Bs + (wn + n * 16 + l15) * 64 + kk + l4 * 8);
#pragma unroll
            for (int m = 0; m < 4; m++)
#pragma unroll
                for (int n = 0; n < 4; n++)
                    acc[m][n] = __builtin_amdgcn_mfma_f32_16x16x32_bf16(
                        af[m], bfv[n], acc[m][n], 0, 0, 0);
        }
        __syncthreads();
    }

#pragma unroll
    for (int m = 0; m < 4; m++) {
#pragma unroll
        for (int n = 0; n < 4; n++) {
#pragma unroll
            for (int j = 0; j < 4; j++) {
                int row = m0 + wm + m * 16 + l4 * 4 + j;
                int col = n0 + wn + n * 16 + l15;
                float v = acc[m][n][j];
                if (bias) v += bias[col];
                size_t idx = (size_t)row * N + col;
                if (epi == 0) {
                    Cb[idx] = f2b(v);
                } else if (epi == 1) {
                    Cf[idx] = v;
                } else if (epi == 3) {
                    Cb[idx] = f2b(fmaxf(v, 0.f));
                } else if (epi == 6) {
                    Cb[idx] = f2b(v + b2f(res[idx]));
                } else {
                    Cf[idx] = v; Cb[idx] = f2b(v);
                }
            }
        }
    }
}

// combined bias for fused embedding: cb[j] = sum_k Ab[k]*Wt[k][j] + tb[j]
__global__ __launch_bounds__(256) void vecmat_bias(const float* __restrict__ Ab,
                                                   const float* __restrict__ Wt,
                                                   const float* __restrict__ tb,
                                                   float* __restrict__ out)
{
    int j = blockIdx.x * 256 + threadIdx.x;   // 1024 total
    float s = tb[j];
    for (int k = 0; k < 1024; k++) s += Ab[k] * Wt[(size_t)k * 1024 + j];
    out[j] = s;
}

// ---------------------------------------------------------------------------
// Self attention (layers 0,1): one block per (b,h). Tq=Tk=32, HD=128.
// PV vectorized: s16x8 V-row reads, 8 outputs per group.
// ---------------------------------------------------------------------------
__global__ __launch_bounds__(256) void attn_self(const short* __restrict__ qkv,
                                                 short* __restrict__ o)
{
    const int b = blockIdx.x >> 3, h = blockIdx.x & 7;
    __shared__ short Q[32 * 128], Kk[32 * 128], Vv[32 * 128];
    __shared__ float S[32 * 32];
    const int tid = threadIdx.x;
    const size_t base = (size_t)b * 32 * 3072 + h * 128;
    for (int i = tid; i < 512; i += 256) {
        int r = i >> 4, c = (i & 15) * 8;
        size_t g = base + (size_t)r * 3072 + c;
        *(s16x8*)(Q  + r * 128 + c) = *(const s16x8*)(qkv + g);
        *(s16x8*)(Kk + r * 128 + c) = *(const s16x8*)(qkv + g + 1024);
        *(s16x8*)(Vv + r * 128 + c) = *(const s16x8*)(qkv + g + 2048);
    }
    __syncthreads();
    for (int i = tid; i < 1024; i += 256) {
        int r = i >> 5, c = i & 31;
        float s = 0.f;
        for (int d8 = 0; d8 < 16; d8++) {
            s16x8 qa = *(const s16x8*)(Q  + r * 128 + d8 * 8);
            s16x8 ka = *(const s16x8*)(Kk + c * 128 + d8 * 8);
#pragma unroll
            for (int j = 0; j < 8; j++) s += b2f(qa[j]) * b2f(ka[j]);
        }
        S[i] = s * 0.088388347648318447f;
    }
    __syncthreads();
    if (tid < 32) {
        float4* row = (float4*)(S + tid * 32);
        float mx = -1e30f;
#pragma unroll
        for (int c = 0; c < 8; c++) {
            float4 v4 = row[c];
            mx = fmaxf(mx, fmaxf(fmaxf(v4.x, v4.y), fmaxf(v4.z, v4.w)));
        }
        float sum = 0.f;
#pragma unroll
        for (int c = 0; c < 8; c++) {
            float4 v4 = row[c];
            v4.x = __expf(v4.x - mx); v4.y = __expf(v4.y - mx);
            v4.z = __expf(v4.z - mx); v4.w = __expf(v4.w - mx);
            sum += v4.x + v4.y + v4.z + v4.w;
            row[c] = v4;
        }
        float inv = 1.f / sum;
#pragma unroll
        for (int c = 0; c < 8; c++) {
            float4 v4 = row[c];
            v4.x *= inv; v4.y *= inv; v4.z *= inv; v4.w *= inv;
            row[c] = v4;
        }
    }
    __syncthreads();
    for (int g = tid; g < 512; g += 256) {
        int r = g >> 4, d0 = (g & 15) * 8;
        float a8[8] = {0.f,0.f,0.f,0.f,0.f,0.f,0.f,0.f};
        for (int c = 0; c < 32; c++) {
            float p = S[r * 32 + c];
            s16x8 v = *(const s16x8*)(Vv + c * 128 + d0);
#pragma unroll
            for (int j = 0; j < 8; j++) a8[j] += p * b2f(v[j]);
        }
        s16x8 ov;
#pragma unroll
        for (int j = 0; j < 8; j++) ov[j] = f2b(a8[j]);
        *(s16x8*)(o + (size_t)(b * 32 + r) * 1024 + h * 128 + d0) = ov;
    }
}

// Cross attention (layers 0,1): Tq=32, Tk=64, key-padding mask (1 = padded).
__global__ __launch_bounds__(256) void attn_cross(const short* __restrict__ q_,
                                                  const short* __restrict__ ckv,
                                                  const int* __restrict__ mask,
                                                  short* __restrict__ o)
{
    const int b = blockIdx.x >> 3, h = blockIdx.x & 7;
    __shared__ short Q[32 * 128], Kk[64 * 128], Vv[64 * 128];
    __shared__ float S[32 * 64];
    const int tid = threadIdx.x;
    for (int i = tid; i < 512; i += 256) {
        int r = i >> 4, c = (i & 15) * 8;
        *(s16x8*)(Q + r * 128 + c) = *(const s16x8*)(q_ + (size_t)(b * 32 + r) * 1024 + h * 128 + c);
    }
    for (int i = tid; i < 1024; i += 256) {
        int r = i >> 4, c = (i & 15) * 8;
        size_t g = (size_t)(b * 64 + r) * 2048 + h * 128 + c;
        *(s16x8*)(Kk + r * 128 + c) = *(const s16x8*)(ckv + g);
        *(s16x8*)(Vv + r * 128 + c) = *(const s16x8*)(ckv + g + 1024);
    }
    __syncthreads();
    for (int i = tid; i < 2048; i += 256) {
        int r = i >> 6, c = i & 63;
        float s = 0.f;
        for (int d8 = 0; d8 < 16; d8++) {
            s16x8 qa = *(const s16x8*)(Q  + r * 128 + d8 * 8);
            s16x8 ka = *(const s16x8*)(Kk + c * 128 + d8 * 8);
#pragma unroll
            for (int j = 0; j < 8; j++) s += b2f(qa[j]) * b2f(ka[j]);
        }
        s *= 0.088388347648318447f;
        if (mask[b * 64 + c] != 0) s = -1e9f;
        S[i] = s;
    }
    __syncthreads();
    if (tid < 32) {
        float4* row = (float4*)(S + tid * 64);
        float mx = -1e30f;
#pragma unroll
        for (int c = 0; c < 16; c++) {
            float4 v4 = row[c];
            mx = fmaxf(mx, fmaxf(fmaxf(v4.x, v4.y), fmaxf(v4.z, v4.w)));
        }
        float sum = 0.f;
#pragma unroll
        for (int c = 0; c < 16; c++) {
            float4 v4 = row[c];
            v4.x = __expf(v4.x - mx); v4.y = __expf(v4.y - mx);
            v4.z = __expf(v4.z - mx); v4.w = __expf(v4.w - mx);
            sum += v4.x + v4.y + v4.z + v4.w;
            row[c] = v4;
        }
        float inv = 1.f / sum;
#pragma unroll
        for (int c = 0; c < 16; c++) {
            float4 v4 = row[c];
            v4.x *= inv; v4.y *= inv; v4.z *= inv; v4.w *= inv;
            row[c] = v4;
        }
    }
    __syncthreads();
    for (int g = tid; g < 512; g += 256) {
        int r = g >> 4, d0 = (g & 15) * 8;
        float a8[8] = {0.f,0.f,0.f,0.f,0.f,0.f,0.f,0.f};
        for (int c = 0; c < 64; c++) {
            float p = S[r * 64 + c];
            s16x8 v = *(const s16x8*)(Vv + c * 128 + d0);
#pragma unroll
            for (int j = 0; j < 8; j++) a8[j] += p * b2f(v[j]);
        }
        s16x8 ov;
#pragma unroll
        for (int j = 0; j < 8; j++) ov[j] = f2b(a8[j]);
        *(s16x8*)(o + (size_t)(b * 32 + r) * 1024 + h * 128 + d0) = ov;
    }
}

// Last-position self attention (layer 3): 1 wave per (b,h).
__global__ __launch_bounds__(256) void attn_self_last(const short* __restrict__ q,
                                                      const short* __restrict__ kv,
                                                      short* __restrict__ out)
{
    __shared__ float qs[4][128];
    __shared__ float ps[4][32];
    const int wave = threadIdx.x >> 6, lane = threadIdx.x & 63;
    const int idx = blockIdx.x * 4 + wave;
    const int b = idx >> 3, h = idx & 7;
    for (int d = lane; d < 128; d += 64)
        qs[wave][d] = b2f(q[(size_t)b * 1024 + h * 128 + d]);
    __syncthreads();
    float s = -1e30f;
    if (lane < 32) {
        const short* kr = kv + (size_t)(b * 32 + lane) * 2048 + h * 128;
        float a = 0.f;
        for (int d = 0; d < 128; d += 8) {
            s16x8 kvv = *(const s16x8*)(kr + d);
#pragma unroll
            for (int j = 0; j < 8; j++) a += qs[wave][d + j] * b2f(kvv[j]);
        }
        s = a * 0.088388347648318447f;
    }
    float mx = s;
#pragma unroll
    for (int o = 1; o < 32; o <<= 1) mx = fmaxf(mx, __shfl_xor(mx, o));
    float p = (lane < 32) ? __expf(s - mx) : 0.f;
    float sum = p;
#pragma unroll
    for (int o = 1; o < 32; o <<= 1) sum += __shfl_xor(sum, o);
    if (lane < 32) ps[wave][lane] = p / sum;
    __syncthreads();
    for (int d = lane; d < 128; d += 64) {
        float a = 0.f;
        for (int j = 0; j < 32; j++)
            a += ps[wave][j] * b2f(kv[(size_t)(b * 32 + j) * 2048 + 1024 + h * 128 + d]);
        out[(size_t)b * 1024 + h * 128 + d] = f2b(a);
    }
}

// Last-position cross attention (layer 3): 1 wave per (b,h); 64 keys + mask.
__global__ __launch_bounds__(256) void attn_cross_last(const short* __restrict__ q,
                                                       const short* __restrict__ ckv,
                                                       const int* __restrict__ mask,
                                                       short* __restrict__ out)
{
    __shared__ float qs[4][128];
    __shared__ float ps[4][64];
    const int wave = threadIdx.x >> 6, lane = threadIdx.x & 63;
    const int idx = blockIdx.x * 4 + wave;
    const int b = idx >> 3, h = idx & 7;
    for (int d = lane; d < 128; d += 64)
        qs[wave][d] = b2f(q[(size_t)b * 1024 + h * 128 + d]);
    __syncthreads();
    const short* kr = ckv + (size_t)(b * 64 + lane) * 2048 + h * 128;
    float a = 0.f;
    for (int d = 0; d < 128; d += 8) {
        s16x8 kvv = *(const s16x8*)(kr + d);
#pragma unroll
        for (int j = 0; j < 8; j++) a += qs[wave][d + j] * b2f(kvv[j]);
    }
    float s = a * 0.088388347648318447f;
    if (mask[b * 64 + lane] != 0) s = -1e9f;
    float mx = s;
#pragma unroll
    for (int o = 1; o < 64; o <<= 1) mx = fmaxf(mx, __shfl_xor(mx, o));
    float p = __expf(s - mx);
    float sum = p;
#pragma unroll
    for (int o = 1; o < 64; o <<= 1) sum += __shfl_xor(sum, o);
    ps[wave][lane] = p / sum;
    __syncthreads();
    for (int d = lane; d < 128; d += 64) {
        float acc = 0.f;
        for (int j = 0; j < 64; j++)
            acc += ps[wave][j] * b2f(ckv[(size_t)(b * 64 + j) * 2048 + 1024 + h * 128 + d]);
        out[(size_t)b * 1024 + h * 128 + d] = f2b(acc);
    }
}

// Row LayerNorm over D=1024, bf16 in -> bf16 out. 128 thr/row (2 waves).
__global__ __launch_bounds__(128) void ln_rows_b(const short* __restrict__ X,
                                                 short* __restrict__ Y,
                                                 const float* __restrict__ g,
                                                 const float* __restrict__ bt)
{
    const int row = blockIdx.x, tid = threadIdx.x;
    s16x8 v = *(const s16x8*)(X + (size_t)row * 1024 + tid * 8);
    float f[8];
    float s = 0.f, q = 0.f;
#pragma unroll
    for (int j = 0; j < 8; j++) { f[j] = b2f(v[j]); s += f[j]; q += f[j] * f[j]; }
#pragma unroll
    for (int o = 1; o < 64; o <<= 1) { s += __shfl_xor(s, o); q += __shfl_xor(q, o); }
    __shared__ float ls[2], lq[2];
    if ((tid & 63) == 0) { ls[tid >> 6] = s; lq[tid >> 6] = q; }
    __syncthreads();
    s = ls[0] + ls[1];
    q = lq[0] + lq[1];
    const float mean = s * 0.0009765625f;
    const float var  = q * 0.0009765625f - mean * mean;
    const float rs = rsqrtf(var + 1e-5f);
    s16x8 ov;
#pragma unroll
    for (int j = 0; j < 8; j++) {
        int c = tid * 8 + j;
        ov[j] = f2b((f[j] - mean) * rs * g[c] + bt[c]);
    }
    *(s16x8*)(Y + (size_t)row * 1024 + tid * 8) = ov;
}

// f32 -> bf16 flat convert (n multiple of 8)
__global__ __launch_bounds__(256) void convf2b(const float* __restrict__ s,
                                               short* __restrict__ d, int n)
{
    int i = (blockIdx.x * 256 + threadIdx.x) * 8;
    if (i < n) {
        float4 a = *(const float4*)(s + i);
        float4 b = *(const float4*)(s + i + 4);
        s16x8 o;
        o[0] = f2b(a.x); o[1] = f2b(a.y); o[2] = f2b(a.z); o[3] = f2b(a.w);
        o[4] = f2b(b.x); o[5] = f2b(b.y); o[6] = f2b(b.z); o[7] = f2b(b.w);
        *(s16x8*)(d + i) = o;
    }
}

// batched f32 [R,C] -> bf16 [C,R] transpose-convert; blockIdx.z = matrix idx
__global__ __launch_bounds__(256) void transpose_conv_b(const float* __restrict__ src0,
                                                        short* __restrict__ dst0,
                                                        int R, int C)
{
    const float* src = src0 + (size_t)blockIdx.z * R * C;
    short* dst = dst0 + (size_t)blockIdx.z * R * C;
    __shared__ float t[32][33];
    int c0 = blockIdx.x * 32, r0 = blockIdx.y * 32;
    int tx = threadIdx.x & 31, ty = threadIdx.x >> 5;
#pragma unroll
    for (int i = 0; i < 32; i += 8) t[ty + i][tx] = src[(size_t)(r0 + ty + i) * C + c0 + tx];
    __syncthreads();
#pragma unroll
    for (int i = 0; i < 32; i += 8) dst[(size_t)(c0 + ty + i) * R + r0 + tx] = f2b(t[tx][ty + i]);
}

// pad rows to 128 (cols=1024), zero-fill beyond src_rows
__global__ __launch_bounds__(256) void pad_conv(const float* __restrict__ s,
                                                short* __restrict__ d, int src_rows)
{
    int i = blockIdx.x * 256 + threadIdx.x;
    int r = i >> 10;
    d[i] = (r < src_rows) ? f2b(s[i]) : (short)0;
}

// positional encoding table [32,1024]
__global__ __launch_bounds__(256) void pe_build(float* __restrict__ pe)
{
    int i = blockIdx.x * 256 + threadIdx.x;
    int t = i >> 10, d = i & 1023;
    int de = d & ~1;
    float ang = (float)t * expf((float)de * (-9.2103403719761836f / 1024.f));
    pe[i] = (d & 1) ? cosf(ang) : sinf(ang);
}

// gather last decode position: xlast[b] = x[b*32+31]
__global__ __launch_bounds__(256) void gather_last(const short* __restrict__ x,
                                                   short* __restrict__ xlast)
{
    int i = blockIdx.x * 256 + threadIdx.x;
    int b = i >> 10, d = i & 1023;
    xlast[i] = x[((size_t)(b * 32 + 31) << 10) + d];
}

// Final routed heads -> nll[b]. One wave per batch element.
__global__ __launch_bounds__(64) void head_final(
    const float* __restrict__ logits_a,
    const float* __restrict__ enc_col_f, const short* __restrict__ yc,
    const float* __restrict__ enc_tab_f, const short* __restrict__ yt,
    const float* __restrict__ outf,
    const float* __restrict__ col_b, const float* __restrict__ tab_b,
    const int* __restrict__ view, const int* __restrict__ ga,
    const int* __restrict__ gc, const int* __restrict__ gt,
    float* __restrict__ nll)
{
    const int b = blockIdx.x, lane = threadIdx.x;
    const int vt = view[b];
    if (vt == 0) {
        float x = logits_a[(size_t)b * 128 + lane];
        float mx = x;
#pragma unroll
        for (int o = 1; o < 64; o <<= 1) mx = fmaxf(mx, __shfl_xor(mx, o));
        float sum = __expf(x - mx);
#pragma unroll
        for (int o = 1; o < 64; o <<= 1) sum += __shfl_xor(sum, o);
        float lse = mx + logf(sum);
        float gl = __shfl(x, ga[b]);
        if (lane == 0) nll[b] = lse - gl;
    } else {
        const int nit = (vt == 1) ? 32 : 16;
        const float* enc = (vt == 1) ? (enc_col_f + (size_t)b * 32 * 1024)
                                     : (enc_tab_f + (size_t)b * 16 * 1024);
        const short* y   = (vt == 1) ? (yc + (size_t)b * 1024) : (yt + (size_t)b * 1024);
        const float* bb  = (vt == 1) ? col_b : tab_b;
        float bc = 0.f;
        for (int i = lane; i < 1024; i += 64) bc += bb[i] * outf[(size_t)b * 1024 + i];
#pragma unroll
        for (int o = 1; o < 64; o <<= 1) bc += __shfl_xor(bc, o);
        float logit = -1e30f;
        if (lane < nit) {
            float s = bc;
            const float* er = enc + (size_t)lane * 1024;
            for (int d8 = 0; d8 < 128; d8++) {
                s16x8 yv = *(const s16x8*)(y + d8 * 8);
                float4 e0 = *(const float4*)(er + d8 * 8);
                float4 e1 = *(const float4*)(er + d8 * 8 + 4);
                s += e0.x * b2f(yv[0]) + e0.y * b2f(yv[1]) + e0.z * b2f(yv[2]) + e0.w * b2f(yv[3])
                   + e1.x * b2f(yv[4]) + e1.y * b2f(yv[5]) + e1.z * b2f(yv[6]) + e1.w * b2f(yv[7]);
            }
            logit = s;
        }
        float mx = logit;
#pragma unroll
        for (int o = 1; o < 64; o <<= 1) mx = fmaxf(mx, __shfl_xor(mx, o));
        float sum = (lane < nit) ? __expf(logit - mx) : 0.f;
#pragma unroll
        for (int o = 1; o < 64; o <<= 1) sum += __shfl_xor(sum, o);
        float lse = mx + logf(sum);
        int g = (vt == 1) ? gc[b] : gt[b];
        float gl = __shfl(logit, g);
        if (lane == 0) nll[b] = lse - gl;
    }
}

// ---------------------------------------------------------------------------
extern "C" void kernel_launch(void* const* d_in, const int* in_sizes, int n_in,
                              void* d_out, int out_size, void* d_ws, size_t ws_size,
                              hipStream_t stream)
{
    const float* pa_f     = (const float*)d_in[0];
    const float* src_f    = (const float*)d_in[1];
    const float* colenc_f = (const float*)d_in[2];
    const float* tabenc_f = (const float*)d_in[3];
    const int*   src_mask = (const int*)d_in[4];
    const int*   sym_ids  = (const int*)d_in[5];
    const int*   view     = (const int*)d_in[6];
    const int*   gold_a   = (const int*)d_in[7];
    const int*   gold_c   = (const int*)d_in[8];
    const int*   gold_t   = (const int*)d_in[9];
    const float* sym_emb  = (const float*)d_in[10];
    const float* act_emb  = (const float*)d_in[11];
    const float* Aaff_w   = (const float*)d_in[12];
    const float* Aaff_b   = (const float*)d_in[13];
    const float* Saff_w   = (const float*)d_in[14];
    const float* Saff_b   = (const float*)d_in[15];
    const float* Caff_w   = (const float*)d_in[16];
    const float* Caff_b   = (const float*)d_in[17];
    const float* Taff_w   = (const float*)d_in[18];
    const float* Taff_b   = (const float*)d_in[19];
    const float* tgt_w    = (const float*)d_in[20];
    const float* tgt_b    = (const float*)d_in[21];
    const float* outw     = (const float*)d_in[22];
    const float* outbias  = (const float*)d_in[23];
    const float* self_w   = (const float*)d_in[24];
    const float* self_b   = (const float*)d_in[25];
    const float* cross_w  = (const float*)d_in[26];
    const float* cross_b  = (const float*)d_in[27];
    const float* f1w      = (const float*)d_in[28];
    const float* f1b      = (const float*)d_in[29];
    const float* f2w      = (const float*)d_in[30];
    const float* f2bb     = (const float*)d_in[31];
    const float* lng      = (const float*)d_in[32];
    const float* lnbt     = (const float*)d_in[33];
    float* nll = (float*)d_out;

    char* ws = (char*)d_ws;
    size_t off = 0;
    auto alloc = [&](size_t bytes) -> char* {
        off = (off + 255) & ~(size_t)255;
        char* p = ws + off; off += bytes; return p;
    };

    const size_t MB1 = (size_t)1024 * 1024;
    short* WAaff  = (short*)alloc(MB1 * 2);
    short* WSaff  = (short*)alloc(MB1 * 2);
    short* Wtop   = (short*)alloc(MB1 * 2);
    short* Wbot   = (short*)alloc(MB1 * 2);
    short* Wout   = (short*)alloc(MB1 * 2);
    short* Wcol   = (short*)alloc(MB1 * 2);
    short* Wtab   = (short*)alloc(MB1 * 2);
    short* Aaffrm = (short*)alloc(MB1 * 2);     // Aaff_w row-major bf16
    short* Wcomb  = (short*)alloc(MB1 * 2);     // (Aaff_w @ Wt_top)^T bf16
    float* cbias  = (float*)alloc(1024 * 4);    // Ab@Wt_top + tgt_b
    short* Wself  = (short*)alloc(12 * MB1 * 2);
    short* Wcross = (short*)alloc(12 * MB1 * 2);
    short* Wf1a   = (short*)alloc(3 * 2 * MB1 * 2);
    short* Wf2a   = (short*)alloc(3 * 2 * MB1 * 2);

    short* src_bf   = (short*)alloc((size_t)16384 * 1024 * 2);
    short* sym_pad  = (short*)alloc((size_t)128 * 1024 * 2);
    short* act_pad  = (short*)alloc((size_t)128 * 1024 * 2);
    short* sa_out   = (short*)alloc((size_t)128 * 1024 * 2);
    float* sym2     = (float*)alloc((size_t)128 * 1024 * 4);
    float* pe       = (float*)alloc((size_t)32 * 1024 * 4);
    short* attn     = (short*)alloc((size_t)8192 * 1024 * 2);
    short* x_bf     = (short*)alloc((size_t)8192 * 1024 * 2);
    short* tmpb     = (short*)alloc((size_t)8192 * 1024 * 2);
    short* arena    = (short*)alloc((size_t)16384 * 2048 * 2);
    short* xlast    = (short*)alloc((size_t)256 * 1024 * 2);
    float* outf     = (float*)alloc((size_t)256 * 1024 * 4);
    short* outb16   = (short*)alloc((size_t)256 * 1024 * 2);
    short* srca     = (short*)alloc((size_t)128 * 1024 * 2);
    float* logits_a = (float*)alloc((size_t)256 * 128 * 4);
    short* ycb      = (short*)alloc((size_t)256 * 1024 * 2);
    short* ytb      = (short*)alloc((size_t)256 * 1024 * 2);
    short* xq31     = (short*)alloc((size_t)256 * 1024 * 2);
    short* x256a    = (short*)alloc((size_t)256 * 1024 * 2);
    short* x256b    = (short*)alloc((size_t)256 * 1024 * 2);
    short* q256     = (short*)alloc((size_t)256 * 1024 * 2);
    short* cq256    = (short*)alloc((size_t)256 * 1024 * 2);
    short* o256     = (short*)alloc((size_t)256 * 1024 * 2);
    short* h256     = (short*)alloc((size_t)256 * 2048 * 2);
    short* tmpb256  = (short*)alloc((size_t)256 * 1024 * 2);

    short* pa_bf = tmpb;   // alias: dead before tmpb first written (layer0 o-proj)
    short* cq    = tmpb;   // alias: live only between LN1 and cross attn

    const dim3 BLK(256);
    auto conv = [&](const float* s, short* d, size_t n) {
        convf2b<<<dim3((unsigned)(n / 8 / 256)), BLK, 0, stream>>>(s, d, (int)n);
    };
    auto trans = [&](const float* s, short* d, int R, int C, int nm) {
        transpose_conv_b<<<dim3(C / 32, R / 32, nm), BLK, 0, stream>>>(s, d, R, C);
    };
    auto gp = [&](const short* A, const short* Bt, const float* bias,
                  short* Cb, const short* res,
                  const float* sy, const int* si, const float* pp,
                  int M, int N, int K, int epi, int BM) {
        if (BM == 256)
            gemm_pipe<256><<<dim3((N / 256) * (M / 256)), dim3(512), 0, stream>>>(
                A, Bt, bias, Cb, res, sy, si, pp, M, N, K, epi);
        else
            gemm_pipe<128><<<dim3((N / 256) * (M / 128)), dim3(512), 0, stream>>>(
                A, Bt, bias, Cb, res, sy, si, pp, M, N, K, epi);
    };
    auto gsm = [&](const short* A, const short* Bt, const float* bias,
                   float* Cf, short* Cb, const short* res,
                   int M, int N, int K, int epi) {
        gemm_bt<<<dim3(N / 128, M / 128), BLK, 0, stream>>>(
            A, Bt, bias, Cf, Cb, res, M, N, K, epi);
    };

    // ---- phase 0: conversions (batched) ----------------------------------
    pe_build<<<dim3(128), BLK, 0, stream>>>(pe);
    conv(pa_f, pa_bf, (size_t)8192 * 1024);
    conv(src_f, src_bf, (size_t)16384 * 1024);
    conv(Caff_w, Wcol, MB1);
    conv(Taff_w, Wtab, MB1);
    conv(Aaff_w, Aaffrm, MB1);
    pad_conv<<<dim3(512), BLK, 0, stream>>>(sym_emb, sym_pad, 32);
    pad_conv<<<dim3(512), BLK, 0, stream>>>(act_emb, act_pad, 64);
    trans(Aaff_w, WAaff, 1024, 1024, 1);
    trans(Saff_w, WSaff, 1024, 1024, 1);
    trans(tgt_w, Wtop, 1024, 1024, 1);
    trans(tgt_w + MB1, Wbot, 1024, 1024, 1);
    trans(outw, Wout, 1024, 1024, 1);
    trans(self_w, Wself, 1024, 1024, 12);
    trans(cross_w, Wcross, 1024, 1024, 12);
    trans(f1w, Wf1a, 1024, 2048, 3);
    trans(f2w, Wf2a, 2048, 1024, 3);

    // ---- phase 1: embeddings (fused affine∘linear) -----------------------
    // Wcomb_bt[n,k] = sum_j Wtop[n,j]*Aaffrm[k,j]  == (Aaff_w @ Wt_top)^T
    gsm(Wtop, Aaffrm, nullptr, nullptr, Wcomb, nullptr, 1024, 1024, 1024, 0);
    vecmat_bias<<<dim3(4), BLK, 0, stream>>>(Aaff_b, tgt_w, tgt_b, cbias);
    gsm(sym_pad, WSaff, Saff_b, nullptr, sa_out, nullptr, 128, 1024, 1024, 0);
    gsm(sa_out, Wbot, nullptr, sym2, nullptr, nullptr, 128, 1024, 1024, 1);
    // x = pa @ Wcomb + cbias + sym2[sid] + pe
    gp(pa_bf, Wcomb, cbias, x_bf, nullptr, sym2, sym_ids, pe,
       8192, 1024, 1024, 2, 128);

    // ---- phase 2: decoder layers 0,1 (full) ------------------------------
    for (int l = 0; l < 2; l++) {
        const float* sb = self_b + (size_t)l * 4096;
        const float* cb = cross_b + (size_t)l * 4096;
        gp(x_bf, Wself + (size_t)(4 * l) * MB1, sb, arena, nullptr, nullptr, nullptr, nullptr,
           8192, 3072, 1024, 0, 256);
        attn_self<<<dim3(2048), BLK, 0, stream>>>(arena, attn);
        gp(attn, Wself + (size_t)(4 * l + 3) * MB1, sb + 3072, tmpb, x_bf, nullptr, nullptr, nullptr,
           8192, 1024, 1024, 6, 128);
        ln_rows_b<<<dim3(8192), dim3(128), 0, stream>>>(tmpb, x_bf,
            lng + (size_t)(l * 3 + 0) * 1024, lnbt + (size_t)(l * 3 + 0) * 1024);
        gp(x_bf, Wcross + (size_t)(4 * l) * MB1, cb, cq, nullptr, nullptr, nullptr, nullptr,
           8192, 1024, 1024, 0, 128);
        gp(src_bf, Wcross + (size_t)(4 * l + 1) * MB1, cb + 1024, arena, nullptr, nullptr, nullptr, nullptr,
           16384, 2048, 1024, 0, 256);
        attn_cross<<<dim3(2048), BLK, 0, stream>>>(cq, arena, src_mask, attn);
        gp(attn, Wcross + (size_t)(4 * l + 3) * MB1, cb + 3072, tmpb, x_bf, nullptr, nullptr, nullptr,
           8192, 1024, 1024, 6, 128);
        ln_rows_b<<<dim3(8192), dim3(128), 0, stream>>>(tmpb, x_bf,
            lng + (size_t)(l * 3 + 1) * 1024, lnbt + (size_t)(l * 3 + 1) * 1024);
        gp(x_bf, Wf1a + (size_t)l * 2 * MB1, f1b + (size_t)l * 2048, arena, nullptr, nullptr, nullptr, nullptr,
           8192, 2048, 1024, 3, 256);
        gp(arena, Wf2a + (size_t)l * 2 * MB1, f2bb + (size_t)l * 1024, tmpb, x_bf, nullptr, nullptr, nullptr,
           8192, 1024, 2048, 6, 128);
        ln_rows_b<<<dim3(8192), dim3(128), 0, stream>>>(tmpb, x_bf,
            lng + (size_t)(l * 3 + 2) * 1024, lnbt + (size_t)(l * 3 + 2) * 1024);
    }

    // ---- layer 2: only last position matters downstream ------------------
    {
        const float* sb = self_b + (size_t)2 * 4096;
        const float* cb = cross_b + (size_t)2 * 4096;
        gather_last<<<dim3(1024), BLK, 0, stream>>>(x_bf, xq31);
        gp(x_bf, Wself + (size_t)(4 * 2 + 1) * MB1, sb + 1024, arena, nullptr, nullptr, nullptr, nullptr,
           8192, 2048, 1024, 0, 256);   // K,V all positions
        gsm(xq31, Wself + (size_t)(4 * 2) * MB1, sb, nullptr, q256, nullptr, 256, 1024, 1024, 0);
        attn_self_last<<<dim3(512), BLK, 0, stream>>>(q256, arena, o256);
        gsm(o256, Wself + (size_t)(4 * 2 + 3) * MB1, sb + 3072, nullptr, tmpb256, xq31, 256, 1024, 1024, 6);
        ln_rows_b<<<dim3(256), dim3(128), 0, stream>>>(tmpb256, x256a,
            lng + (size_t)(2 * 3 + 0) * 1024, lnbt + (size_t)(2 * 3 + 0) * 1024);
        gsm(x256a, Wcross + (size_t)(4 * 2) * MB1, cb, nullptr, cq256, nullptr, 256, 1024, 1024, 0);
        gp(src_bf, Wcross + (size_t)(4 * 2 + 1) * MB1, cb + 1024, arena, nullptr, nullptr, nullptr, nullptr,
           16384, 2048, 1024, 0, 256);
        attn_cross_last<<<dim3(512), BLK, 0, stream>>>(cq256, arena, src_mask, o256);
        gsm(o256, Wcross + (size_t)(4 * 2 + 3) * MB1, cb + 3072, nullptr, tmpb256, x256a, 256, 1024, 1024, 6);
        ln_rows_b<<<dim3(256), dim3(128), 0, stream>>>(tmpb256, x256b,
            lng + (size_t)(2 * 3 + 1) * 1024, lnbt + (size_t)(2 * 3 + 1) * 1024);
        gsm(x256b, Wf1a + (size_t)2 * 2 * MB1, f1b + (size_t)2 * 2048, nullptr, h256, nullptr,
            256, 2048, 1024, 3);
        gsm(h256, Wf2a + (size_t)2 * 2 * MB1, f2bb + (size_t)2 * 1024, nullptr, tmpb256, x256b,
            256, 1024, 2048, 6);
        ln_rows_b<<<dim3(256), dim3(128), 0, stream>>>(tmpb256, xlast,
            lng + (size_t)(2 * 3 + 2) * 1024, lnbt + (size_t)(2 * 3 + 2) * 1024);
    }

    // ---- phase 3: heads --------------------------------------------------
    gsm(xlast, Wout, outbias, outf, outb16, nullptr, 256, 1024, 1024, 5);
    gsm(act_pad, WAaff, Aaff_b, nullptr, srca, nullptr, 128, 1024, 1024, 0);
    gsm(outb16, srca, nullptr, logits_a, nullptr, nullptr, 256, 128, 1024, 1);
    gsm(outb16, Wcol, nullptr, nullptr, ycb, nullptr, 256, 1024, 1024, 0);
    gsm(outb16, Wtab, nullptr, nullptr, ytb, nullptr, 256, 1024, 1024, 0);
    head_final<<<dim3(256), dim3(64), 0, stream>>>(
        logits_a, colenc_f, ycb, tabenc_f, ytb, outf,
        Caff_b, Taff_b, view, gold_a, gold_c, gold_t, nll);
}

// Round 11
// 2276.800 us; speedup vs baseline: 2.0845x; 1.1133x over previous
//
#include <hip/hip_runtime.h>

typedef float  f32x4 __attribute__((ext_vector_type(4)));
typedef short  s16x8 __attribute__((ext_vector_type(8)));

__device__ __forceinline__ float b2f(short s) {
    return __uint_as_float(((unsigned)(unsigned short)s) << 16);
}
__device__ __forceinline__ short f2b(float f) {
    unsigned u = __float_as_uint(f);
    u = u + 0x7fffu + ((u >> 16) & 1u);
    return (short)(u >> 16);
}

// async global->LDS, 16B per lane; LDS dest = wave-uniform base + lane*16
__device__ __forceinline__ void gld_lds16(const short* g, short* l) {
    __builtin_amdgcn_global_load_lds(
        (const __attribute__((address_space(1))) unsigned int*)(const void*)g,
        (__attribute__((address_space(3))) unsigned int*)(void*)l,
        16, 0, 0);
}

// ---------------------------------------------------------------------------
// Occupancy-first bf16 GEMM: C[M,N] = A[M,K]*Bt[N,K]^T (+bias).
// 64x128 tile, 256 thr = 4 waves (2M x 2N), per-wave out 32x64, BK=64,
// SINGLE 24.5KB LDS buffer, __launch_bounds__(256,4) caps regs at 128
// (acc 32 AGPR + ~70 VGPR) -> 4 blocks/CU = 16 waves/CU (50% occupancy).
// Rationale (r10 counters): all schedules at >=128KB LDS were latency-bound
// (MfmaUtil 12%, VALU 8%, HBM 8%, Occ 20%) -- lockstep waves of ONE block
// can't hide stage latency. 4 independent blocks/CU hide each other's
// stalls (m114 mechanism). Simple 2-barrier loop; swizzle as rounds 5-10
// (slot s of row r holds global chunk s^(r&7); 0 conflicts measured).
// epi: 0 Cb=bf16(v)  2 Cb=bf16(v+sym2[sid[row]]+pe[row&31])
//      3 Cb=bf16(relu v)  6 Cb=bf16(v+res[idx])
// ---------------------------------------------------------------------------
__global__ __launch_bounds__(256, 4) void gemm_hi(
    const short* __restrict__ A, const short* __restrict__ Bt,
    const float* __restrict__ bias,
    short* __restrict__ Cb,
    const short* __restrict__ res,
    const float* __restrict__ sym2, const int* __restrict__ sid,
    const float* __restrict__ pe,
    int M, int N, int K, int epi)
{
    __shared__ short lds[(64 + 128) * 64];    // A [64][64] + B [128][64]

    const int tid  = threadIdx.x;
    const int lane = tid & 63;
    const int w    = tid >> 6;

    int bid = blockIdx.x;
    int nwg = gridDim.x;
    if ((nwg & 7) == 0) { int q = nwg >> 3; bid = (bid & 7) * q + (bid >> 3); }
    const int nbx = N >> 7;
    const int m0 = (bid / nbx) * 64;
    const int n0 = (bid % nbx) * 128;

    const int wm = (w >> 1) * 32;
    const int wn = (w & 1) * 64;
    const int l15 = lane & 15, l4 = lane >> 4;
    const int key = lane & 7;

    f32x4 acc[2][4];
#pragma unroll
    for (int m = 0; m < 2; m++)
#pragma unroll
        for (int n = 0; n < 4; n++)
#pragma unroll
            for (int j = 0; j < 4; j++) acc[m][n][j] = 0.f;

    // ds_read byte offsets (k-step 0; step 1 = ^64)
    int aoff[2], boff[4];
#pragma unroll
    for (int m = 0; m < 2; m++) {
        int r = wm + m * 16 + l15;
        aoff[m] = r * 128 + ((l4 ^ key) << 4);
    }
#pragma unroll
    for (int n = 0; n < 4; n++) {
        int r = wn + n * 16 + l15;
        boff[n] = 64 * 128 + r * 128 + ((l4 ^ key) << 4);
    }

    // stage: lane -> row lane>>3 within 8-row group, src chunk (lane&7)^(lane>>3)
    const int lrow = lane >> 3;
    const int lchunk = (lane & 7) ^ lrow;
    size_t agoff[2]; int aldo[2];
#pragma unroll
    for (int i = 0; i < 2; i++) {
        int rr = w * 16 + i * 8;
        agoff[i] = (size_t)(m0 + rr + lrow) * K + lchunk * 8;
        aldo[i]  = rr * 128;
    }
    size_t bgoff[4]; int bldo[4];
#pragma unroll
    for (int i = 0; i < 4; i++) {
        int rr = w * 32 + i * 8;
        bgoff[i] = (size_t)(n0 + rr + lrow) * K + lchunk * 8;
        bldo[i]  = 64 * 128 + rr * 128;
    }

    char* lb = (char*)lds;
    const int NT = K >> 6;
    for (int t = 0; t < NT; t++) {
        const size_t ke = (size_t)t * 64;
#pragma unroll
        for (int i = 0; i < 2; i++)
            gld_lds16(A + agoff[i] + ke, (short*)(lb + aldo[i]));
#pragma unroll
        for (int i = 0; i < 4; i++)
            gld_lds16(Bt + bgoff[i] + ke, (short*)(lb + bldo[i]));
        __syncthreads();
#pragma unroll
        for (int ks = 0; ks < 2; ks++) {
            const int x = ks ? 64 : 0;
            s16x8 af[2], bv[4];
#pragma unroll
            for (int m = 0; m < 2; m++) af[m] = *(const s16x8*)(lb + (aoff[m] ^ x));
#pragma unroll
            for (int n = 0; n < 4; n++)  bv[n] = *(const s16x8*)(lb + (boff[n] ^ x));
#pragma unroll
            for (int m = 0; m < 2; m++)
#pragma unroll
                for (int n = 0; n < 4; n++)
                    acc[m][n] = __builtin_amdgcn_mfma_f32_16x16x32_bf16(
                        af[m], bv[n], acc[m][n], 0, 0, 0);
        }
        __syncthreads();
    }

    // ---- epilogue --------------------------------------------------------
#pragma unroll
    for (int m = 0; m < 2; m++) {
#pragma unroll
        for (int n = 0; n < 4; n++) {
#pragma unroll
            for (int j = 0; j < 4; j++) {
                int row = m0 + wm + m * 16 + l4 * 4 + j;
                int col = n0 + wn + n * 16 + l15;
                float v = acc[m][n][j];
                if (bias) v += bias[col];
                size_t idx = (size_t)row * N + col;
                if (epi == 0) {
                    Cb[idx] = f2b(v);
                } else if (epi == 2) {
                    v += sym2[(size_t)sid[row] * 1024 + col] + pe[(size_t)(row & 31) * 1024 + col];
                    Cb[idx] = f2b(v);
                } else if (epi == 3) {
                    Cb[idx] = f2b(fmaxf(v, 0.f));
                } else {
                    Cb[idx] = f2b(v + b2f(res[idx]));
                }
            }
        }
    }
}

// ---------------------------------------------------------------------------
// Small-M GEMM (M=128..1024): 128x128 tile, 4 waves, gld_lds staging.
// epi: 0 Cb=bf16(v)  1 Cf=v  3 relu  5 Cf=v & Cb=bf16(v)  6 Cb=bf16(v+res)
// ---------------------------------------------------------------------------
__global__ __launch_bounds__(256) void gemm_bt(
    const short* __restrict__ A, const short* __restrict__ Bt,
    const float* __restrict__ bias,
    float* __restrict__ Cf, short* __restrict__ Cb,
    const short* __restrict__ res,
    int M, int N, int K, int epi)
{
    __shared__ short As[128 * 64];
    __shared__ short Bs[128 * 64];
    const int tid  = threadIdx.x;
    const int lane = tid & 63;
    const int wave = tid >> 6;
    const int m0 = blockIdx.y * 128, n0 = blockIdx.x * 128;
    const int wm = (wave >> 1) * 64, wn = (wave & 1) * 64;
    const int l15 = lane & 15, l4 = lane >> 4;

    f32x4 acc[4][4];
#pragma unroll
    for (int m = 0; m < 4; m++)
#pragma unroll
        for (int n = 0; n < 4; n++)
#pragma unroll
            for (int j = 0; j < 4; j++) acc[m][n][j] = 0.f;

    const int srow = wave * 32 + (lane >> 3);
    const int scol = (lane & 7) * 8;
    const short* Ag = A  + (size_t)(m0 + srow) * K + scol;
    const short* Bg = Bt + (size_t)(n0 + srow) * K + scol;
    short* Al = As + (wave * 32) * 64;
    short* Bl = Bs + (wave * 32) * 64;

    for (int k0 = 0; k0 < K; k0 += 64) {
#pragma unroll
        for (int i = 0; i < 4; i++) {
            gld_lds16(Ag + (size_t)(i * 8) * K + k0, Al + i * 8 * 64);
            gld_lds16(Bg + (size_t)(i * 8) * K + k0, Bl + i * 8 * 64);
        }
        __syncthreads();
#pragma unroll
        for (int kk = 0; kk < 64; kk += 32) {
            s16x8 af[4], bfv[4];
#pragma unroll
            for (int m = 0; m < 4; m++)
                af[m] = *(const s16x8*)(As + (wm + m * 16 + l15) * 64 + kk + l4 * 8);
#pragma unroll
            for (int n = 0; n < 4; n++)
                bfv[n] = *(const s16x8*)(Bs + (wn + n * 16 + l15) * 64 + kk + l4 * 8);
#pragma unroll
            for (int m = 0; m < 4; m++)
#pragma unroll
                for (int n = 0; n < 4; n++)
                    acc[m][n] = __builtin_amdgcn_mfma_f32_16x16x32_bf16(
                        af[m], bfv[n], acc[m][n], 0, 0, 0);
        }
        __syncthreads();
    }

#pragma unroll
    for (int m = 0; m < 4; m++) {
#pragma unroll
        for (int n = 0; n < 4; n++) {
#pragma unroll
            for (int j = 0; j < 4; j++) {
                int row = m0 + wm + m * 16 + l4 * 4 + j;
                int col = n0 + wn + n * 16 + l15;
                float v = acc[m][n][j];
                if (bias) v += bias[col];
                size_t idx = (size_t)row * N + col;
                if (epi == 0) {
                    Cb[idx] = f2b(v);
                } else if (epi == 1) {
                    Cf[idx] = v;
                } else if (epi == 3) {
                    Cb[idx] = f2b(fmaxf(v, 0.f));
                } else if (epi == 6) {
                    Cb[idx] = f2b(v + b2f(res[idx]));
                } else {
                    Cf[idx] = v; Cb[idx] = f2b(v);
                }
            }
        }
    }
}

// combined bias for fused embedding: cb[j] = sum_k Ab[k]*Wt[k][j] + tb[j]
__global__ __launch_bounds__(256) void vecmat_bias(const float* __restrict__ Ab,
                                                   const float* __restrict__ Wt,
                                                   const float* __restrict__ tb,
                                                   float* __restrict__ out)
{
    int j = blockIdx.x * 256 + threadIdx.x;   // 1024 total
    float s = tb[j];
    for (int k = 0; k < 1024; k++) s += Ab[k] * Wt[(size_t)k * 1024 + j];
    out[j] = s;
}

// ---------------------------------------------------------------------------
// Self attention (layers 0,1): one block per (b,h). Tq=Tk=32, HD=128.
// ---------------------------------------------------------------------------
__global__ __launch_bounds__(256) void attn_self(const short* __restrict__ qkv,
                                                 short* __restrict__ o)
{
    const int b = blockIdx.x >> 3, h = blockIdx.x & 7;
    __shared__ short Q[32 * 128], Kk[32 * 128], Vv[32 * 128];
    __shared__ float S[32 * 32];
    const int tid = threadIdx.x;
    const size_t base = (size_t)b * 32 * 3072 + h * 128;
    for (int i = tid; i < 512; i += 256) {
        int r = i >> 4, c = (i & 15) * 8;
        size_t g = base + (size_t)r * 3072 + c;
        *(s16x8*)(Q  + r * 128 + c) = *(const s16x8*)(qkv + g);
        *(s16x8*)(Kk + r * 128 + c) = *(const s16x8*)(qkv + g + 1024);
        *(s16x8*)(Vv + r * 128 + c) = *(const s16x8*)(qkv + g + 2048);
    }
    __syncthreads();
    for (int i = tid; i < 1024; i += 256) {
        int r = i >> 5, c = i & 31;
        float s = 0.f;
        for (int d8 = 0; d8 < 16; d8++) {
            s16x8 qa = *(const s16x8*)(Q  + r * 128 + d8 * 8);
            s16x8 ka = *(const s16x8*)(Kk + c * 128 + d8 * 8);
#pragma unroll
            for (int j = 0; j < 8; j++) s += b2f(qa[j]) * b2f(ka[j]);
        }
        S[i] = s * 0.088388347648318447f;
    }
    __syncthreads();
    if (tid < 32) {
        float4* row = (float4*)(S + tid * 32);
        float mx = -1e30f;
#pragma unroll
        for (int c = 0; c < 8; c++) {
            float4 v4 = row[c];
            mx = fmaxf(mx, fmaxf(fmaxf(v4.x, v4.y), fmaxf(v4.z, v4.w)));
        }
        float sum = 0.f;
#pragma unroll
        for (int c = 0; c < 8; c++) {
            float4 v4 = row[c];
            v4.x = __expf(v4.x - mx); v4.y = __expf(v4.y - mx);
            v4.z = __expf(v4.z - mx); v4.w = __expf(v4.w - mx);
            sum += v4.x + v4.y + v4.z + v4.w;
            row[c] = v4;
        }
        float inv = 1.f / sum;
#pragma unroll
        for (int c = 0; c < 8; c++) {
            float4 v4 = row[c];
            v4.x *= inv; v4.y *= inv; v4.z *= inv; v4.w *= inv;
            row[c] = v4;
        }
    }
    __syncthreads();
    for (int g = tid; g < 512; g += 256) {
        int r = g >> 4, d0 = (g & 15) * 8;
        float a8[8] = {0.f,0.f,0.f,0.f,0.f,0.f,0.f,0.f};
        for (int c = 0; c < 32; c++) {
            float p = S[r * 32 + c];
            s16x8 v = *(const s16x8*)(Vv + c * 128 + d0);
#pragma unroll
            for (int j = 0; j < 8; j++) a8[j] += p * b2f(v[j]);
        }
        s16x8 ov;
#pragma unroll
        for (int j = 0; j < 8; j++) ov[j] = f2b(a8[j]);
        *(s16x8*)(o + (size_t)(b * 32 + r) * 1024 + h * 128 + d0) = ov;
    }
}

// Cross attention (layers 0,1): Tq=32, Tk=64, key-padding mask (1 = padded).
__global__ __launch_bounds__(256) void attn_cross(const short* __restrict__ q_,
                                                  const short* __restrict__ ckv,
                                                  const int* __restrict__ mask,
                                                  short* __restrict__ o)
{
    const int b = blockIdx.x >> 3, h = blockIdx.x & 7;
    __shared__ short Q[32 * 128], Kk[64 * 128], Vv[64 * 128];
    __shared__ float S[32 * 64];
    const int tid = threadIdx.x;
    for (int i = tid; i < 512; i += 256) {
        int r = i >> 4, c = (i & 15) * 8;
        *(s16x8*)(Q + r * 128 + c) = *(const s16x8*)(q_ + (size_t)(b * 32 + r) * 1024 + h * 128 + c);
    }
    for (int i = tid; i < 1024; i += 256) {
        int r = i >> 4, c = (i & 15) * 8;
        size_t g = (size_t)(b * 64 + r) * 2048 + h * 128 + c;
        *(s16x8*)(Kk + r * 128 + c) = *(const s16x8*)(ckv + g);
        *(s16x8*)(Vv + r * 128 + c) = *(const s16x8*)(ckv + g + 1024);
    }
    __syncthreads();
    for (int i = tid; i < 2048; i += 256) {
        int r = i >> 6, c = i & 63;
        float s = 0.f;
        for (int d8 = 0; d8 < 16; d8++) {
            s16x8 qa = *(const s16x8*)(Q  + r * 128 + d8 * 8);
            s16x8 ka = *(const s16x8*)(Kk + c * 128 + d8 * 8);
#pragma unroll
            for (int j = 0; j < 8; j++) s += b2f(qa[j]) * b2f(ka[j]);
        }
        s *= 0.088388347648318447f;
        if (mask[b * 64 + c] != 0) s = -1e9f;
        S[i] = s;
    }
    __syncthreads();
    if (tid < 32) {
        float4* row = (float4*)(S + tid * 64);
        float mx = -1e30f;
#pragma unroll
        for (int c = 0; c < 16; c++) {
            float4 v4 = row[c];
            mx = fmaxf(mx, fmaxf(fmaxf(v4.x, v4.y), fmaxf(v4.z, v4.w)));
        }
        float sum = 0.f;
#pragma unroll
        for (int c = 0; c < 16; c++) {
            float4 v4 = row[c];
            v4.x = __expf(v4.x - mx); v4.y = __expf(v4.y - mx);
            v4.z = __expf(v4.z - mx); v4.w = __expf(v4.w - mx);
            sum += v4.x + v4.y + v4.z + v4.w;
            row[c] = v4;
        }
        float inv = 1.f / sum;
#pragma unroll
        for (int c = 0; c < 16; c++) {
            float4 v4 = row[c];
            v4.x *= inv; v4.y *= inv; v4.z *= inv; v4.w *= inv;
            row[c] = v4;
        }
    }
    __syncthreads();
    for (int g = tid; g < 512; g += 256) {
        int r = g >> 4, d0 = (g & 15) * 8;
        float a8[8] = {0.f,0.f,0.f,0.f,0.f,0.f,0.f,0.f};
        for (int c = 0; c < 64; c++) {
            float p = S[r * 64 + c];
            s16x8 v = *(const s16x8*)(Vv + c * 128 + d0);
#pragma unroll
            for (int j = 0; j < 8; j++) a8[j] += p * b2f(v[j]);
        }
        s16x8 ov;
#pragma unroll
        for (int j = 0; j < 8; j++) ov[j] = f2b(a8[j]);
        *(s16x8*)(o + (size_t)(b * 32 + r) * 1024 + h * 128 + d0) = ov;
    }
}

// Last-position self attention (layer 3): 1 wave per (b,h).
__global__ __launch_bounds__(256) void attn_self_last(const short* __restrict__ q,
                                                      const short* __restrict__ kv,
                                                      short* __restrict__ out)
{
    __shared__ float qs[4][128];
    __shared__ float ps[4][32];
    const int wave = threadIdx.x >> 6, lane = threadIdx.x & 63;
    const int idx = blockIdx.x * 4 + wave;
    const int b = idx >> 3, h = idx & 7;
    for (int d = lane; d < 128; d += 64)
        qs[wave][d] = b2f(q[(size_t)b * 1024 + h * 128 + d]);
    __syncthreads();
    float s = -1e30f;
    if (lane < 32) {
        const short* kr = kv + (size_t)(b * 32 + lane) * 2048 + h * 128;
        float a = 0.f;
        for (int d = 0; d < 128; d += 8) {
            s16x8 kvv = *(const s16x8*)(kr + d);
#pragma unroll
            for (int j = 0; j < 8; j++) a += qs[wave][d + j] * b2f(kvv[j]);
        }
        s = a * 0.088388347648318447f;
    }
    float mx = s;
#pragma unroll
    for (int o = 1; o < 32; o <<= 1) mx = fmaxf(mx, __shfl_xor(mx, o));
    float p = (lane < 32) ? __expf(s - mx) : 0.f;
    float sum = p;
#pragma unroll
    for (int o = 1; o < 32; o <<= 1) sum += __shfl_xor(sum, o);
    if (lane < 32) ps[wave][lane] = p / sum;
    __syncthreads();
    for (int d = lane; d < 128; d += 64) {
        float a = 0.f;
        for (int j = 0; j < 32; j++)
            a += ps[wave][j] * b2f(kv[(size_t)(b * 32 + j) * 2048 + 1024 + h * 128 + d]);
        out[(size_t)b * 1024 + h * 128 + d] = f2b(a);
    }
}

// Last-position cross attention (layer 3): 1 wave per (b,h); 64 keys + mask.
__global__ __launch_bounds__(256) void attn_cross_last(const short* __restrict__ q,
                                                       const short* __restrict__ ckv,
                                                       const int* __restrict__ mask,
                                                       short* __restrict__ out)
{
    __shared__ float qs[4][128];
    __shared__ float ps[4][64];
    const int wave = threadIdx.x >> 6, lane = threadIdx.x & 63;
    const int idx = blockIdx.x * 4 + wave;
    const int b = idx >> 3, h = idx & 7;
    for (int d = lane; d < 128; d += 64)
        qs[wave][d] = b2f(q[(size_t)b * 1024 + h * 128 + d]);
    __syncthreads();
    const short* kr = ckv + (size_t)(b * 64 + lane) * 2048 + h * 128;
    float a = 0.f;
    for (int d = 0; d < 128; d += 8) {
        s16x8 kvv = *(const s16x8*)(kr + d);
#pragma unroll
        for (int j = 0; j < 8; j++) a += qs[wave][d + j] * b2f(kvv[j]);
    }
    float s = a * 0.088388347648318447f;
    if (mask[b * 64 + lane] != 0) s = -1e9f;
    float mx = s;
#pragma unroll
    for (int o = 1; o < 64; o <<= 1) mx = fmaxf(mx, __shfl_xor(mx, o));
    float p = __expf(s - mx);
    float sum = p;
#pragma unroll
    for (int o = 1; o < 64; o <<= 1) sum += __shfl_xor(sum, o);
    ps[wave][lane] = p / sum;
    __syncthreads();
    for (int d = lane; d < 128; d += 64) {
        float acc = 0.f;
        for (int j = 0; j < 64; j++)
            acc += ps[wave][j] * b2f(ckv[(size_t)(b * 64 + j) * 2048 + 1024 + h * 128 + d]);
        out[(size_t)b * 1024 + h * 128 + d] = f2b(acc);
    }
}

// Row LayerNorm over D=1024, bf16 in -> bf16 out. 128 thr/row (2 waves).
__global__ __launch_bounds__(128) void ln_rows_b(const short* __restrict__ X,
                                                 short* __restrict__ Y,
                                                 const float* __restrict__ g,
                                                 const float* __restrict__ bt)
{
    const int row = blockIdx.x, tid = threadIdx.x;
    s16x8 v = *(const s16x8*)(X + (size_t)row * 1024 + tid * 8);
    float f[8];
    float s = 0.f, q = 0.f;
#pragma unroll
    for (int j = 0; j < 8; j++) { f[j] = b2f(v[j]); s += f[j]; q += f[j] * f[j]; }
#pragma unroll
    for (int o = 1; o < 64; o <<= 1) { s += __shfl_xor(s, o); q += __shfl_xor(q, o); }
    __shared__ float ls[2], lq[2];
    if ((tid & 63) == 0) { ls[tid >> 6] = s; lq[tid >> 6] = q; }
    __syncthreads();
    s = ls[0] + ls[1];
    q = lq[0] + lq[1];
    const float mean = s * 0.0009765625f;
    const float var  = q * 0.0009765625f - mean * mean;
    const float rs = rsqrtf(var + 1e-5f);
    s16x8 ov;
#pragma unroll
    for (int j = 0; j < 8; j++) {
        int c = tid * 8 + j;
        ov[j] = f2b((f[j] - mean) * rs * g[c] + bt[c]);
    }
    *(s16x8*)(Y + (size_t)row * 1024 + tid * 8) = ov;
}

// f32 -> bf16 flat convert (n multiple of 8)
__global__ __launch_bounds__(256) void convf2b(const float* __restrict__ s,
                                               short* __restrict__ d, int n)
{
    int i = (blockIdx.x * 256 + threadIdx.x) * 8;
    if (i < n) {
        float4 a = *(const float4*)(s + i);
        float4 b = *(const float4*)(s + i + 4);
        s16x8 o;
        o[0] = f2b(a.x); o[1] = f2b(a.y); o[2] = f2b(a.z); o[3] = f2b(a.w);
        o[4] = f2b(b.x); o[5] = f2b(b.y); o[6] = f2b(b.z); o[7] = f2b(b.w);
        *(s16x8*)(d + i) = o;
    }
}

// batched f32 [R,C] -> bf16 [C,R] transpose-convert; blockIdx.z = matrix idx
__global__ __launch_bounds__(256) void transpose_conv_b(const float* __restrict__ src0,
                                                        short* __restrict__ dst0,
                                                        int R, int C)
{
    const float* src = src0 + (size_t)blockIdx.z * R * C;
    short* dst = dst0 + (size_t)blockIdx.z * R * C;
    __shared__ float t[32][33];
    int c0 = blockIdx.x * 32, r0 = blockIdx.y * 32;
    int tx = threadIdx.x & 31, ty = threadIdx.x >> 5;
#pragma unroll
    for (int i = 0; i < 32; i += 8) t[ty + i][tx] = src[(size_t)(r0 + ty + i) * C + c0 + tx];
    __syncthreads();
#pragma unroll
    for (int i = 0; i < 32; i += 8) dst[(size_t)(c0 + ty + i) * R + r0 + tx] = f2b(t[tx][ty + i]);
}

// pad rows to 128 (cols=1024), zero-fill beyond src_rows
__global__ __launch_bounds__(256) void pad_conv(const float* __restrict__ s,
                                                short* __restrict__ d, int src_rows)
{
    int i = blockIdx.x * 256 + threadIdx.x;
    int r = i >> 10;
    d[i] = (r < src_rows) ? f2b(s[i]) : (short)0;
}

// positional encoding table [32,1024]
__global__ __launch_bounds__(256) void pe_build(float* __restrict__ pe)
{
    int i = blockIdx.x * 256 + threadIdx.x;
    int t = i >> 10, d = i & 1023;
    int de = d & ~1;
    float ang = (float)t * expf((float)de * (-9.2103403719761836f / 1024.f));
    pe[i] = (d & 1) ? cosf(ang) : sinf(ang);
}

// gather last decode position: xlast[b] = x[b*32+31]
__global__ __launch_bounds__(256) void gather_last(const short* __restrict__ x,
                                                   short* __restrict__ xlast)
{
    int i = blockIdx.x * 256 + threadIdx.x;
    int b = i >> 10, d = i & 1023;
    xlast[i] = x[((size_t)(b * 32 + 31) << 10) + d];
}

// Final routed heads -> nll[b]. One wave per batch element.
__global__ __launch_bounds__(64) void head_final(
    const float* __restrict__ logits_a,
    const float* __restrict__ enc_col_f, const short* __restrict__ yc,
    const float* __restrict__ enc_tab_f, const short* __restrict__ yt,
    const float* __restrict__ outf,
    const float* __restrict__ col_b, const float* __restrict__ tab_b,
    const int* __restrict__ view, const int* __restrict__ ga,
    const int* __restrict__ gc, const int* __restrict__ gt,
    float* __restrict__ nll)
{
    const int b = blockIdx.x, lane = threadIdx.x;
    const int vt = view[b];
    if (vt == 0) {
        float x = logits_a[(size_t)b * 128 + lane];
        float mx = x;
#pragma unroll
        for (int o = 1; o < 64; o <<= 1) mx = fmaxf(mx, __shfl_xor(mx, o));
        float sum = __expf(x - mx);
#pragma unroll
        for (int o = 1; o < 64; o <<= 1) sum += __shfl_xor(sum, o);
        float lse = mx + logf(sum);
        float gl = __shfl(x, ga[b]);
        if (lane == 0) nll[b] = lse - gl;
    } else {
        const int nit = (vt == 1) ? 32 : 16;
        const float* enc = (vt == 1) ? (enc_col_f + (size_t)b * 32 * 1024)
                                     : (enc_tab_f + (size_t)b * 16 * 1024);
        const short* y   = (vt == 1) ? (yc + (size_t)b * 1024) : (yt + (size_t)b * 1024);
        const float* bb  = (vt == 1) ? col_b : tab_b;
        float bc = 0.f;
        for (int i = lane; i < 1024; i += 64) bc += bb[i] * outf[(size_t)b * 1024 + i];
#pragma unroll
        for (int o = 1; o < 64; o <<= 1) bc += __shfl_xor(bc, o);
        float logit = -1e30f;
        if (lane < nit) {
            float s = bc;
            const float* er = enc + (size_t)lane * 1024;
            for (int d8 = 0; d8 < 128; d8++) {
                s16x8 yv = *(const s16x8*)(y + d8 * 8);
                float4 e0 = *(const float4*)(er + d8 * 8);
                float4 e1 = *(const float4*)(er + d8 * 8 + 4);
                s += e0.x * b2f(yv[0]) + e0.y * b2f(yv[1]) + e0.z * b2f(yv[2]) + e0.w * b2f(yv[3])
                   + e1.x * b2f(yv[4]) + e1.y * b2f(yv[5]) + e1.z * b2f(yv[6]) + e1.w * b2f(yv[7]);
            }
            logit = s;
        }
        float mx = logit;
#pragma unroll
        for (int o = 1; o < 64; o <<= 1) mx = fmaxf(mx, __shfl_xor(mx, o));
        float sum = (lane < nit) ? __expf(logit - mx) : 0.f;
#pragma unroll
        for (int o = 1; o < 64; o <<= 1) sum += __shfl_xor(sum, o);
        float lse = mx + logf(sum);
        int g = (vt == 1) ? gc[b] : gt[b];
        float gl = __shfl(logit, g);
        if (lane == 0) nll[b] = lse - gl;
    }
}

// ---------------------------------------------------------------------------
extern "C" void kernel_launch(void* const* d_in, const int* in_sizes, int n_in,
                              void* d_out, int out_size, void* d_ws, size_t ws_size,
                              hipStream_t stream)
{
    const float* pa_f     = (const float*)d_in[0];
    const float* src_f    = (const float*)d_in[1];
    const float* colenc_f = (const float*)d_in[2];
    const float* tabenc_f = (const float*)d_in[3];
    const int*   src_mask = (const int*)d_in[4];
    const int*   sym_ids  = (const int*)d_in[5];
    const int*   view     = (const int*)d_in[6];
    const int*   gold_a   = (const int*)d_in[7];
    const int*   gold_c   = (const int*)d_in[8];
    const int*   gold_t   = (const int*)d_in[9];
    const float* sym_emb  = (const float*)d_in[10];
    const float* act_emb  = (const float*)d_in[11];
    const float* Aaff_w   = (const float*)d_in[12];
    const float* Aaff_b   = (const float*)d_in[13];
    const float* Saff_w   = (const float*)d_in[14];
    const float* Saff_b   = (const float*)d_in[15];
    const float* Caff_w   = (const float*)d_in[16];
    const float* Caff_b   = (const float*)d_in[17];
    const float* Taff_w   = (const float*)d_in[18];
    const float* Taff_b   = (const float*)d_in[19];
    const float* tgt_w    = (const float*)d_in[20];
    const float* tgt_b    = (const float*)d_in[21];
    const float* outw     = (const float*)d_in[22];
    const float* outbias  = (const float*)d_in[23];
    const float* self_w   = (const float*)d_in[24];
    const float* self_b   = (const float*)d_in[25];
    const float* cross_w  = (const float*)d_in[26];
    const float* cross_b  = (const float*)d_in[27];
    const float* f1w      = (const float*)d_in[28];
    const float* f1b      = (const float*)d_in[29];
    const float* f2w      = (const float*)d_in[30];
    const float* f2bb     = (const float*)d_in[31];
    const float* lng      = (const float*)d_in[32];
    const float* lnbt     = (const float*)d_in[33];
    float* nll = (float*)d_out;

    char* ws = (char*)d_ws;
    size_t off = 0;
    auto alloc = [&](size_t bytes) -> char* {
        off = (off + 255) & ~(size_t)255;
        char* p = ws + off; off += bytes; return p;
    };

    const size_t MB1 = (size_t)1024 * 1024;
    short* WAaff  = (short*)alloc(MB1 * 2);
    short* WSaff  = (short*)alloc(MB1 * 2);
    short* Wtop   = (short*)alloc(MB1 * 2);
    short* Wbot   = (short*)alloc(MB1 * 2);
    short* Wout   = (short*)alloc(MB1 * 2);
    short* Wcol   = (short*)alloc(MB1 * 2);
    short* Wtab   = (short*)alloc(MB1 * 2);
    short* Aaffrm = (short*)alloc(MB1 * 2);
    short* Wcomb  = (short*)alloc(MB1 * 2);
    float* cbias  = (float*)alloc(1024 * 4);
    short* Wself  = (short*)alloc(12 * MB1 * 2);
    short* Wcross = (short*)alloc(12 * MB1 * 2);
    short* Wf1a   = (short*)alloc(3 * 2 * MB1 * 2);
    short* Wf2a   = (short*)alloc(3 * 2 * MB1 * 2);

    short* src_bf   = (short*)alloc((size_t)16384 * 1024 * 2);
    short* sym_pad  = (short*)alloc((size_t)128 * 1024 * 2);
    short* act_pad  = (short*)alloc((size_t)128 * 1024 * 2);
    short* sa_out   = (short*)alloc((size_t)128 * 1024 * 2);
    float* sym2     = (float*)alloc((size_t)128 * 1024 * 4);
    float* pe       = (float*)alloc((size_t)32 * 1024 * 4);
    short* attn     = (short*)alloc((size_t)8192 * 1024 * 2);
    short* x_bf     = (short*)alloc((size_t)8192 * 1024 * 2);
    short* tmpb     = (short*)alloc((size_t)8192 * 1024 * 2);
    short* arena    = (short*)alloc((size_t)16384 * 2048 * 2);
    short* xlast    = (short*)alloc((size_t)256 * 1024 * 2);
    float* outf     = (float*)alloc((size_t)256 * 1024 * 4);
    short* outb16   = (short*)alloc((size_t)256 * 1024 * 2);
    short* srca     = (short*)alloc((size_t)128 * 1024 * 2);
    float* logits_a = (float*)alloc((size_t)256 * 128 * 4);
    short* ycb      = (short*)alloc((size_t)256 * 1024 * 2);
    short* ytb      = (short*)alloc((size_t)256 * 1024 * 2);
    short* xq31     = (short*)alloc((size_t)256 * 1024 * 2);
    short* x256a    = (short*)alloc((size_t)256 * 1024 * 2);
    short* x256b    = (short*)alloc((size_t)256 * 1024 * 2);
    short* q256     = (short*)alloc((size_t)256 * 1024 * 2);
    short* cq256    = (short*)alloc((size_t)256 * 1024 * 2);
    short* o256     = (short*)alloc((size_t)256 * 1024 * 2);
    short* h256     = (short*)alloc((size_t)256 * 2048 * 2);
    short* tmpb256  = (short*)alloc((size_t)256 * 1024 * 2);

    short* pa_bf = tmpb;   // alias: dead before tmpb first written (layer0 o-proj)
    short* cq    = tmpb;   // alias: live only between LN1 and cross attn

    const dim3 BLK(256);
    auto conv = [&](const float* s, short* d, size_t n) {
        convf2b<<<dim3((unsigned)(n / 8 / 256)), BLK, 0, stream>>>(s, d, (int)n);
    };
    auto trans = [&](const float* s, short* d, int R, int C, int nm) {
        transpose_conv_b<<<dim3(C / 32, R / 32, nm), BLK, 0, stream>>>(s, d, R, C);
    };
    auto gh = [&](const short* A, const short* Bt, const float* bias,
                  short* Cb, const short* res,
                  const float* sy, const int* si, const float* pp,
                  int M, int N, int K, int epi) {
        gemm_hi<<<dim3((N / 128) * (M / 64)), BLK, 0, stream>>>(
            A, Bt, bias, Cb, res, sy, si, pp, M, N, K, epi);
    };
    auto gsm = [&](const short* A, const short* Bt, const float* bias,
                   float* Cf, short* Cb, const short* res,
                   int M, int N, int K, int epi) {
        gemm_bt<<<dim3(N / 128, M / 128), BLK, 0, stream>>>(
            A, Bt, bias, Cf, Cb, res, M, N, K, epi);
    };

    // ---- phase 0: conversions (batched) ----------------------------------
    pe_build<<<dim3(128), BLK, 0, stream>>>(pe);
    conv(pa_f, pa_bf, (size_t)8192 * 1024);
    conv(src_f, src_bf, (size_t)16384 * 1024);
    conv(Caff_w, Wcol, MB1);
    conv(Taff_w, Wtab, MB1);
    conv(Aaff_w, Aaffrm, MB1);
    pad_conv<<<dim3(512), BLK, 0, stream>>>(sym_emb, sym_pad, 32);
    pad_conv<<<dim3(512), BLK, 0, stream>>>(act_emb, act_pad, 64);
    trans(Aaff_w, WAaff, 1024, 1024, 1);
    trans(Saff_w, WSaff, 1024, 1024, 1);
    trans(tgt_w, Wtop, 1024, 1024, 1);
    trans(tgt_w + MB1, Wbot, 1024, 1024, 1);
    trans(outw, Wout, 1024, 1024, 1);
    trans(self_w, Wself, 1024, 1024, 12);
    trans(cross_w, Wcross, 1024, 1024, 12);
    trans(f1w, Wf1a, 1024, 2048, 3);
    trans(f2w, Wf2a, 2048, 1024, 3);

    // ---- phase 1: embeddings (fused affine∘linear) -----------------------
    gsm(Wtop, Aaffrm, nullptr, nullptr, Wcomb, nullptr, 1024, 1024, 1024, 0);
    vecmat_bias<<<dim3(4), BLK, 0, stream>>>(Aaff_b, tgt_w, tgt_b, cbias);
    gsm(sym_pad, WSaff, Saff_b, nullptr, sa_out, nullptr, 128, 1024, 1024, 0);
    gsm(sa_out, Wbot, nullptr, sym2, nullptr, nullptr, 128, 1024, 1024, 1);
    gh(pa_bf, Wcomb, cbias, x_bf, nullptr, sym2, sym_ids, pe,
       8192, 1024, 1024, 2);

    // ---- phase 2: decoder layers 0,1 (full) ------------------------------
    for (int l = 0; l < 2; l++) {
        const float* sb = self_b + (size_t)l * 4096;
        const float* cb = cross_b + (size_t)l * 4096;
        gh(x_bf, Wself + (size_t)(4 * l) * MB1, sb, arena, nullptr, nullptr, nullptr, nullptr,
           8192, 3072, 1024, 0);
        attn_self<<<dim3(2048), BLK, 0, stream>>>(arena, attn);
        gh(attn, Wself + (size_t)(4 * l + 3) * MB1, sb + 3072, tmpb, x_bf, nullptr, nullptr, nullptr,
           8192, 1024, 1024, 6);
        ln_rows_b<<<dim3(8192), dim3(128), 0, stream>>>(tmpb, x_bf,
            lng + (size_t)(l * 3 + 0) * 1024, lnbt + (size_t)(l * 3 + 0) * 1024);
        gh(x_bf, Wcross + (size_t)(4 * l) * MB1, cb, cq, nullptr, nullptr, nullptr, nullptr,
           8192, 1024, 1024, 0);
        gh(src_bf, Wcross + (size_t)(4 * l + 1) * MB1, cb + 1024, arena, nullptr, nullptr, nullptr, nullptr,
           16384, 2048, 1024, 0);
        attn_cross<<<dim3(2048), BLK, 0, stream>>>(cq, arena, src_mask, attn);
        gh(attn, Wcross + (size_t)(4 * l + 3) * MB1, cb + 3072, tmpb, x_bf, nullptr, nullptr, nullptr,
           8192, 1024, 1024, 6);
        ln_rows_b<<<dim3(8192), dim3(128), 0, stream>>>(tmpb, x_bf,
            lng + (size_t)(l * 3 + 1) * 1024, lnbt + (size_t)(l * 3 + 1) * 1024);
        gh(x_bf, Wf1a + (size_t)l * 2 * MB1, f1b + (size_t)l * 2048, arena, nullptr, nullptr, nullptr, nullptr,
           8192, 2048, 1024, 3);
        gh(arena, Wf2a + (size_t)l * 2 * MB1, f2bb + (size_t)l * 1024, tmpb, x_bf, nullptr, nullptr, nullptr,
           8192, 1024, 2048, 6);
        ln_rows_b<<<dim3(8192), dim3(128), 0, stream>>>(tmpb, x_bf,
            lng + (size_t)(l * 3 + 2) * 1024, lnbt + (size_t)(l * 3 + 2) * 1024);
    }

    // ---- layer 2: only last position matters downstream ------------------
    {
        const float* sb = self_b + (size_t)2 * 4096;
        const float* cb = cross_b + (size_t)2 * 4096;
        gather_last<<<dim3(1024), BLK, 0, stream>>>(x_bf, xq31);
        gh(x_bf, Wself + (size_t)(4 * 2 + 1) * MB1, sb + 1024, arena, nullptr, nullptr, nullptr, nullptr,
           8192, 2048, 1024, 0);   // K,V all positions
        gsm(xq31, Wself + (size_t)(4 * 2) * MB1, sb, nullptr, q256, nullptr, 256, 1024, 1024, 0);
        attn_self_last<<<dim3(512), BLK, 0, stream>>>(q256, arena, o256);
        gsm(o256, Wself + (size_t)(4 * 2 + 3) * MB1, sb + 3072, nullptr, tmpb256, xq31, 256, 1024, 1024, 6);
        ln_rows_b<<<dim3(256), dim3(128), 0, stream>>>(tmpb256, x256a,
            lng + (size_t)(2 * 3 + 0) * 1024, lnbt + (size_t)(2 * 3 + 0) * 1024);
        gsm(x256a, Wcross + (size_t)(4 * 2) * MB1, cb, nullptr, cq256, nullptr, 256, 1024, 1024, 0);
        gh(src_bf, Wcross + (size_t)(4 * 2 + 1) * MB1, cb + 1024, arena, nullptr, nullptr, nullptr, nullptr,
           16384, 2048, 1024, 0);
        attn_cross_last<<<dim3(512), BLK, 0, stream>>>(cq256, arena, src_mask, o256);
        gsm(o256, Wcross + (size_t)(4 * 2 + 3) * MB1, cb + 3072, nullptr, tmpb256, x256a, 256, 1024, 1024, 6);
        ln_rows_b<<<dim3(256), dim3(128), 0, stream>>>(tmpb256, x256b,
            lng + (size_t)(2 * 3 + 1) * 1024, lnbt + (size_t)(2 * 3 + 1) * 1024);
        gsm(x256b, Wf1a + (size_t)2 * 2 * MB1, f1b + (size_t)2 * 2048, nullptr, h256, nullptr,
            256, 2048, 1024, 3);
        gsm(h256, Wf2a + (size_t)2 * 2 * MB1, f2bb + (size_t)2 * 1024, nullptr, tmpb256, x256b,
            256, 1024, 2048, 6);
        ln_rows_b<<<dim3(256), dim3(128), 0, stream>>>(tmpb256, xlast,
            lng + (size_t)(2 * 3 + 2) * 1024, lnbt + (size_t)(2 * 3 + 2) * 1024);
    }

    // ---- phase 3: heads --------------------------------------------------
    gsm(xlast, Wout, outbias, outf, outb16, nullptr, 256, 1024, 1024, 5);
    gsm(act_pad, WAaff, Aaff_b, nullptr, srca, nullptr, 128, 1024, 1024, 0);
    gsm(outb16, srca, nullptr, logits_a, nullptr, nullptr, 256, 128, 1024, 1);
    gsm(outb16, Wcol, nullptr, nullptr, ycb, nullptr, 256, 1024, 1024, 0);
    gsm(outb16, Wtab, nullptr, nullptr, ytb, nullptr, 256, 1024, 1024, 0);
    head_final<<<dim3(256), dim3(64), 0, stream>>>(
        logits_a, colenc_f, ycb, tabenc_f, ytb, outf,
        Caff_b, Taff_b, view, gold_a, gold_c, gold_t, nll);
}

// Round 12
// 2197.188 us; speedup vs baseline: 2.1601x; 1.0362x over previous
//
#include <hip/hip_runtime.h>

typedef float  f32x4 __attribute__((ext_vector_type(4)));
typedef short  s16x8 __attribute__((ext_vector_type(8)));

__device__ __forceinline__ float b2f(short s) {
    return __uint_as_float(((unsigned)(unsigned short)s) << 16);
}
__device__ __forceinline__ short f2b(float f) {
    unsigned u = __float_as_uint(f);
    u = u + 0x7fffu + ((u >> 16) & 1u);
    return (short)(u >> 16);
}

// async global->LDS, 16B per lane; LDS dest = wave-uniform base + lane*16
__device__ __forceinline__ void gld_lds16(const short* g, short* l) {
    __builtin_amdgcn_global_load_lds(
        (const __attribute__((address_space(1))) unsigned int*)(const void*)g,
        (__attribute__((address_space(3))) unsigned int*)(void*)l,
        16, 0, 0);
}

// ---------------------------------------------------------------------------
// Occupancy-first bf16 GEMM: C[M,N] = A[M,K]*Bt[N,K]^T (+bias).
// 64x128 tile, 256 thr = 4 waves (2M x 2N), per-wave out 32x64, BK=64,
// SINGLE 24.5KB LDS buffer, __launch_bounds__(256,6) -> 6 blocks/CU
// (LDS 6x24.5=147KB <= 160KB; regs 44 VGPR + 32 AGPR = 76 <= 512/6=85)
// = 24 waves/CU (75% occupancy). r11 A/B: 4 blocks/CU gave Occ 20->47%,
// MfmaUtil 12->21%, ckv 165->137us -- independent blocks hide each other's
// stage latency (m114). This pushes the same confirmed lever further.
// Swizzle (0 conflicts measured): slot s of row r holds global chunk s^(r&7).
// epi: 0 Cb=bf16(v)  2 Cb=bf16(v+sym2[sid[row]]+pe[row&31])
//      3 Cb=bf16(relu v)  6 Cb=bf16(v+res[idx])
// ---------------------------------------------------------------------------
__global__ __launch_bounds__(256, 6) void gemm_hi(
    const short* __restrict__ A, const short* __restrict__ Bt,
    const float* __restrict__ bias,
    short* __restrict__ Cb,
    const short* __restrict__ res,
    const float* __restrict__ sym2, const int* __restrict__ sid,
    const float* __restrict__ pe,
    int M, int N, int K, int epi)
{
    __shared__ short lds[(64 + 128) * 64];    // A [64][64] + B [128][64]

    const int tid  = threadIdx.x;
    const int lane = tid & 63;
    const int w    = tid >> 6;

    int bid = blockIdx.x;
    int nwg = gridDim.x;
    if ((nwg & 7) == 0) { int q = nwg >> 3; bid = (bid & 7) * q + (bid >> 3); }
    const int nbx = N >> 7;
    const int m0 = (bid / nbx) * 64;
    const int n0 = (bid % nbx) * 128;

    const int wm = (w >> 1) * 32;
    const int wn = (w & 1) * 64;
    const int l15 = lane & 15, l4 = lane >> 4;
    const int key = lane & 7;

    f32x4 acc[2][4];
#pragma unroll
    for (int m = 0; m < 2; m++)
#pragma unroll
        for (int n = 0; n < 4; n++)
#pragma unroll
            for (int j = 0; j < 4; j++) acc[m][n][j] = 0.f;

    // ds_read byte offsets (k-step 0; step 1 = ^64)
    int aoff[2], boff[4];
#pragma unroll
    for (int m = 0; m < 2; m++) {
        int r = wm + m * 16 + l15;
        aoff[m] = r * 128 + ((l4 ^ key) << 4);
    }
#pragma unroll
    for (int n = 0; n < 4; n++) {
        int r = wn + n * 16 + l15;
        boff[n] = 64 * 128 + r * 128 + ((l4 ^ key) << 4);
    }

    // stage: lane -> row lane>>3 within 8-row group, src chunk (lane&7)^(lane>>3)
    const int lrow = lane >> 3;
    const int lchunk = (lane & 7) ^ lrow;
    size_t agoff[2]; int aldo[2];
#pragma unroll
    for (int i = 0; i < 2; i++) {
        int rr = w * 16 + i * 8;
        agoff[i] = (size_t)(m0 + rr + lrow) * K + lchunk * 8;
        aldo[i]  = rr * 128;
    }
    size_t bgoff[4]; int bldo[4];
#pragma unroll
    for (int i = 0; i < 4; i++) {
        int rr = w * 32 + i * 8;
        bgoff[i] = (size_t)(n0 + rr + lrow) * K + lchunk * 8;
        bldo[i]  = 64 * 128 + rr * 128;
    }

    char* lb = (char*)lds;
    const int NT = K >> 6;
    for (int t = 0; t < NT; t++) {
        const size_t ke = (size_t)t * 64;
#pragma unroll
        for (int i = 0; i < 2; i++)
            gld_lds16(A + agoff[i] + ke, (short*)(lb + aldo[i]));
#pragma unroll
        for (int i = 0; i < 4; i++)
            gld_lds16(Bt + bgoff[i] + ke, (short*)(lb + bldo[i]));
        __syncthreads();
#pragma unroll
        for (int ks = 0; ks < 2; ks++) {
            const int x = ks ? 64 : 0;
            s16x8 af[2], bv[4];
#pragma unroll
            for (int m = 0; m < 2; m++) af[m] = *(const s16x8*)(lb + (aoff[m] ^ x));
#pragma unroll
            for (int n = 0; n < 4; n++)  bv[n] = *(const s16x8*)(lb + (boff[n] ^ x));
#pragma unroll
            for (int m = 0; m < 2; m++)
#pragma unroll
                for (int n = 0; n < 4; n++)
                    acc[m][n] = __builtin_amdgcn_mfma_f32_16x16x32_bf16(
                        af[m], bv[n], acc[m][n], 0, 0, 0);
        }
        __syncthreads();
    }

    // ---- epilogue --------------------------------------------------------
#pragma unroll
    for (int m = 0; m < 2; m++) {
#pragma unroll
        for (int n = 0; n < 4; n++) {
#pragma unroll
            for (int j = 0; j < 4; j++) {
                int row = m0 + wm + m * 16 + l4 * 4 + j;
                int col = n0 + wn + n * 16 + l15;
                float v = acc[m][n][j];
                if (bias) v += bias[col];
                size_t idx = (size_t)row * N + col;
                if (epi == 0) {
                    Cb[idx] = f2b(v);
                } else if (epi == 2) {
                    v += sym2[(size_t)sid[row] * 1024 + col] + pe[(size_t)(row & 31) * 1024 + col];
                    Cb[idx] = f2b(v);
                } else if (epi == 3) {
                    Cb[idx] = f2b(fmaxf(v, 0.f));
                } else {
                    Cb[idx] = f2b(v + b2f(res[idx]));
                }
            }
        }
    }
}

// ---------------------------------------------------------------------------
// Small-M GEMM (M=128..1024): 128x128 tile, 4 waves, gld_lds staging.
// __launch_bounds__(256,4): 64 AGPR + ~55 VGPR <= 128, LDS 32KBx4 = 128KB
// -> 4 blocks/CU (was 2-3 waves/SIMD of one block).
// epi: 0 Cb=bf16(v)  1 Cf=v  3 relu  5 Cf=v & Cb=bf16(v)  6 Cb=bf16(v+res)
// ---------------------------------------------------------------------------
__global__ __launch_bounds__(256, 4) void gemm_bt(
    const short* __restrict__ A, const short* __restrict__ Bt,
    const float* __restrict__ bias,
    float* __restrict__ Cf, short* __restrict__ Cb,
    const short* __restrict__ res,
    int M, int N, int K, int epi)
{
    __shared__ short As[128 * 64];
    __shared__ short Bs[128 * 64];
    const int tid  = threadIdx.x;
    const int lane = tid & 63;
    const int wave = tid >> 6;
    const int m0 = blockIdx.y * 128, n0 = blockIdx.x * 128;
    const int wm = (wave >> 1) * 64, wn = (wave & 1) * 64;
    const int l15 = lane & 15, l4 = lane >> 4;

    f32x4 acc[4][4];
#pragma unroll
    for (int m = 0; m < 4; m++)
#pragma unroll
        for (int n = 0; n < 4; n++)
#pragma unroll
            for (int j = 0; j < 4; j++) acc[m][n][j] = 0.f;

    const int srow = wave * 32 + (lane >> 3);
    const int scol = (lane & 7) * 8;
    const short* Ag = A  + (size_t)(m0 + srow) * K + scol;
    const short* Bg = Bt + (size_t)(n0 + srow) * K + scol;
    short* Al = As + (wave * 32) * 64;
    short* Bl = Bs + (wave * 32) * 64;

    for (int k0 = 0; k0 < K; k0 += 64) {
#pragma unroll
        for (int i = 0; i < 4; i++) {
            gld_lds16(Ag + (size_t)(i * 8) * K + k0, Al + i * 8 * 64);
            gld_lds16(Bg + (size_t)(i * 8) * K + k0, Bl + i * 8 * 64);
        }
        __syncthreads();
#pragma unroll
        for (int kk = 0; kk < 64; kk += 32) {
            s16x8 af[4], bfv[4];
#pragma unroll
            for (int m = 0; m < 4; m++)
                af[m] = *(const s16x8*)(As + (wm + m * 16 + l15) * 64 + kk + l4 * 8);
#pragma unroll
            for (int n = 0; n < 4; n++)
                bfv[n] = *(const s16x8*)(Bs + (wn + n * 16 + l15) * 64 + kk + l4 * 8);
#pragma unroll
            for (int m = 0; m < 4; m++)
#pragma unroll
                for (int n = 0; n < 4; n++)
                    acc[m][n] = __builtin_amdgcn_mfma_f32_16x16x32_bf16(
                        af[m], bfv[n], acc[m][n], 0, 0, 0);
        }
        __syncthreads();
    }

#pragma unroll
    for (int m = 0; m < 4; m++) {
#pragma unroll
        for (int n = 0; n < 4; n++) {
#pragma unroll
            for (int j = 0; j < 4; j++) {
                int row = m0 + wm + m * 16 + l4 * 4 + j;
                int col = n0 + wn + n * 16 + l15;
                float v = acc[m][n][j];
                if (bias) v += bias[col];
                size_t idx = (size_t)row * N + col;
                if (epi == 0) {
                    Cb[idx] = f2b(v);
                } else if (epi == 1) {
                    Cf[idx] = v;
                } else if (epi == 3) {
                    Cb[idx] = f2b(fmaxf(v, 0.f));
                } else if (epi == 6) {
                    Cb[idx] = f2b(v + b2f(res[idx]));
                } else {
                    Cf[idx] = v; Cb[idx] = f2b(v);
                }
            }
        }
    }
}

// combined bias for fused embedding: cb[j] = sum_k Ab[k]*Wt[k][j] + tb[j]
__global__ __launch_bounds__(256) void vecmat_bias(const float* __restrict__ Ab,
                                                   const float* __restrict__ Wt,
                                                   const float* __restrict__ tb,
                                                   float* __restrict__ out)
{
    int j = blockIdx.x * 256 + threadIdx.x;   // 1024 total
    float s = tb[j];
    for (int k = 0; k < 1024; k++) s += Ab[k] * Wt[(size_t)k * 1024 + j];
    out[j] = s;
}

// ---------------------------------------------------------------------------
// Self attention (layers 0,1): one block per (b,h). Tq=Tk=32, HD=128.
// ---------------------------------------------------------------------------
__global__ __launch_bounds__(256) void attn_self(const short* __restrict__ qkv,
                                                 short* __restrict__ o)
{
    const int b = blockIdx.x >> 3, h = blockIdx.x & 7;
    __shared__ short Q[32 * 128], Kk[32 * 128], Vv[32 * 128];
    __shared__ float S[32 * 32];
    const int tid = threadIdx.x;
    const size_t base = (size_t)b * 32 * 3072 + h * 128;
    for (int i = tid; i < 512; i += 256) {
        int r = i >> 4, c = (i & 15) * 8;
        size_t g = base + (size_t)r * 3072 + c;
        *(s16x8*)(Q  + r * 128 + c) = *(const s16x8*)(qkv + g);
        *(s16x8*)(Kk + r * 128 + c) = *(const s16x8*)(qkv + g + 1024);
        *(s16x8*)(Vv + r * 128 + c) = *(const s16x8*)(qkv + g + 2048);
    }
    __syncthreads();
    for (int i = tid; i < 1024; i += 256) {
        int r = i >> 5, c = i & 31;
        float s = 0.f;
        for (int d8 = 0; d8 < 16; d8++) {
            s16x8 qa = *(const s16x8*)(Q  + r * 128 + d8 * 8);
            s16x8 ka = *(const s16x8*)(Kk + c * 128 + d8 * 8);
#pragma unroll
            for (int j = 0; j < 8; j++) s += b2f(qa[j]) * b2f(ka[j]);
        }
        S[i] = s * 0.088388347648318447f;
    }
    __syncthreads();
    if (tid < 32) {
        float4* row = (float4*)(S + tid * 32);
        float mx = -1e30f;
#pragma unroll
        for (int c = 0; c < 8; c++) {
            float4 v4 = row[c];
            mx = fmaxf(mx, fmaxf(fmaxf(v4.x, v4.y), fmaxf(v4.z, v4.w)));
        }
        float sum = 0.f;
#pragma unroll
        for (int c = 0; c < 8; c++) {
            float4 v4 = row[c];
            v4.x = __expf(v4.x - mx); v4.y = __expf(v4.y - mx);
            v4.z = __expf(v4.z - mx); v4.w = __expf(v4.w - mx);
            sum += v4.x + v4.y + v4.z + v4.w;
            row[c] = v4;
        }
        float inv = 1.f / sum;
#pragma unroll
        for (int c = 0; c < 8; c++) {
            float4 v4 = row[c];
            v4.x *= inv; v4.y *= inv; v4.z *= inv; v4.w *= inv;
            row[c] = v4;
        }
    }
    __syncthreads();
    for (int g = tid; g < 512; g += 256) {
        int r = g >> 4, d0 = (g & 15) * 8;
        float a8[8] = {0.f,0.f,0.f,0.f,0.f,0.f,0.f,0.f};
        for (int c = 0; c < 32; c++) {
            float p = S[r * 32 + c];
            s16x8 v = *(const s16x8*)(Vv + c * 128 + d0);
#pragma unroll
            for (int j = 0; j < 8; j++) a8[j] += p * b2f(v[j]);
        }
        s16x8 ov;
#pragma unroll
        for (int j = 0; j < 8; j++) ov[j] = f2b(a8[j]);
        *(s16x8*)(o + (size_t)(b * 32 + r) * 1024 + h * 128 + d0) = ov;
    }
}

// Cross attention (layers 0,1): Tq=32, Tk=64, key-padding mask (1 = padded).
__global__ __launch_bounds__(256) void attn_cross(const short* __restrict__ q_,
                                                  const short* __restrict__ ckv,
                                                  const int* __restrict__ mask,
                                                  short* __restrict__ o)
{
    const int b = blockIdx.x >> 3, h = blockIdx.x & 7;
    __shared__ short Q[32 * 128], Kk[64 * 128], Vv[64 * 128];
    __shared__ float S[32 * 64];
    const int tid = threadIdx.x;
    for (int i = tid; i < 512; i += 256) {
        int r = i >> 4, c = (i & 15) * 8;
        *(s16x8*)(Q + r * 128 + c) = *(const s16x8*)(q_ + (size_t)(b * 32 + r) * 1024 + h * 128 + c);
    }
    for (int i = tid; i < 1024; i += 256) {
        int r = i >> 4, c = (i & 15) * 8;
        size_t g = (size_t)(b * 64 + r) * 2048 + h * 128 + c;
        *(s16x8*)(Kk + r * 128 + c) = *(const s16x8*)(ckv + g);
        *(s16x8*)(Vv + r * 128 + c) = *(const s16x8*)(ckv + g + 1024);
    }
    __syncthreads();
    for (int i = tid; i < 2048; i += 256) {
        int r = i >> 6, c = i & 63;
        float s = 0.f;
        for (int d8 = 0; d8 < 16; d8++) {
            s16x8 qa = *(const s16x8*)(Q  + r * 128 + d8 * 8);
            s16x8 ka = *(const s16x8*)(Kk + c * 128 + d8 * 8);
#pragma unroll
            for (int j = 0; j < 8; j++) s += b2f(qa[j]) * b2f(ka[j]);
        }
        s *= 0.088388347648318447f;
        if (mask[b * 64 + c] != 0) s = -1e9f;
        S[i] = s;
    }
    __syncthreads();
    if (tid < 32) {
        float4* row = (float4*)(S + tid * 64);
        float mx = -1e30f;
#pragma unroll
        for (int c = 0; c < 16; c++) {
            float4 v4 = row[c];
            mx = fmaxf(mx, fmaxf(fmaxf(v4.x, v4.y), fmaxf(v4.z, v4.w)));
        }
        float sum = 0.f;
#pragma unroll
        for (int c = 0; c < 16; c++) {
            float4 v4 = row[c];
            v4.x = __expf(v4.x - mx); v4.y = __expf(v4.y - mx);
            v4.z = __expf(v4.z - mx); v4.w = __expf(v4.w - mx);
            sum += v4.x + v4.y + v4.z + v4.w;
            row[c] = v4;
        }
        float inv = 1.f / sum;
#pragma unroll
        for (int c = 0; c < 16; c++) {
            float4 v4 = row[c];
            v4.x *= inv; v4.y *= inv; v4.z *= inv; v4.w *= inv;
            row[c] = v4;
        }
    }
    __syncthreads();
    for (int g = tid; g < 512; g += 256) {
        int r = g >> 4, d0 = (g & 15) * 8;
        float a8[8] = {0.f,0.f,0.f,0.f,0.f,0.f,0.f,0.f};
        for (int c = 0; c < 64; c++) {
            float p = S[r * 64 + c];
            s16x8 v = *(const s16x8*)(Vv + c * 128 + d0);
#pragma unroll
            for (int j = 0; j < 8; j++) a8[j] += p * b2f(v[j]);
        }
        s16x8 ov;
#pragma unroll
        for (int j = 0; j < 8; j++) ov[j] = f2b(a8[j]);
        *(s16x8*)(o + (size_t)(b * 32 + r) * 1024 + h * 128 + d0) = ov;
    }
}

// Last-position self attention (layer 3): 1 wave per (b,h).
__global__ __launch_bounds__(256) void attn_self_last(const short* __restrict__ q,
                                                      const short* __restrict__ kv,
                                                      short* __restrict__ out)
{
    __shared__ float qs[4][128];
    __shared__ float ps[4][32];
    const int wave = threadIdx.x >> 6, lane = threadIdx.x & 63;
    const int idx = blockIdx.x * 4 + wave;
    const int b = idx >> 3, h = idx & 7;
    for (int d = lane; d < 128; d += 64)
        qs[wave][d] = b2f(q[(size_t)b * 1024 + h * 128 + d]);
    __syncthreads();
    float s = -1e30f;
    if (lane < 32) {
        const short* kr = kv + (size_t)(b * 32 + lane) * 2048 + h * 128;
        float a = 0.f;
        for (int d = 0; d < 128; d += 8) {
            s16x8 kvv = *(const s16x8*)(kr + d);
#pragma unroll
            for (int j = 0; j < 8; j++) a += qs[wave][d + j] * b2f(kvv[j]);
        }
        s = a * 0.088388347648318447f;
    }
    float mx = s;
#pragma unroll
    for (int o = 1; o < 32; o <<= 1) mx = fmaxf(mx, __shfl_xor(mx, o));
    float p = (lane < 32) ? __expf(s - mx) : 0.f;
    float sum = p;
#pragma unroll
    for (int o = 1; o < 32; o <<= 1) sum += __shfl_xor(sum, o);
    if (lane < 32) ps[wave][lane] = p / sum;
    __syncthreads();
    for (int d = lane; d < 128; d += 64) {
        float a = 0.f;
        for (int j = 0; j < 32; j++)
            a += ps[wave][j] * b2f(kv[(size_t)(b * 32 + j) * 2048 + 1024 + h * 128 + d]);
        out[(size_t)b * 1024 + h * 128 + d] = f2b(a);
    }
}

// Last-position cross attention (layer 3): 1 wave per (b,h); 64 keys + mask.
__global__ __launch_bounds__(256) void attn_cross_last(const short* __restrict__ q,
                                                       const short* __restrict__ ckv,
                                                       const int* __restrict__ mask,
                                                       short* __restrict__ out)
{
    __shared__ float qs[4][128];
    __shared__ float ps[4][64];
    const int wave = threadIdx.x >> 6, lane = threadIdx.x & 63;
    const int idx = blockIdx.x * 4 + wave;
    const int b = idx >> 3, h = idx & 7;
    for (int d = lane; d < 128; d += 64)
        qs[wave][d] = b2f(q[(size_t)b * 1024 + h * 128 + d]);
    __syncthreads();
    const short* kr = ckv + (size_t)(b * 64 + lane) * 2048 + h * 128;
    float a = 0.f;
    for (int d = 0; d < 128; d += 8) {
        s16x8 kvv = *(const s16x8*)(kr + d);
#pragma unroll
        for (int j = 0; j < 8; j++) a += qs[wave][d + j] * b2f(kvv[j]);
    }
    float s = a * 0.088388347648318447f;
    if (mask[b * 64 + lane] != 0) s = -1e9f;
    float mx = s;
#pragma unroll
    for (int o = 1; o < 64; o <<= 1) mx = fmaxf(mx, __shfl_xor(mx, o));
    float p = __expf(s - mx);
    float sum = p;
#pragma unroll
    for (int o = 1; o < 64; o <<= 1) sum += __shfl_xor(sum, o);
    ps[wave][lane] = p / sum;
    __syncthreads();
    for (int d = lane; d < 128; d += 64) {
        float acc = 0.f;
        for (int j = 0; j < 64; j++)
            acc += ps[wave][j] * b2f(ckv[(size_t)(b * 64 + j) * 2048 + 1024 + h * 128 + d]);
        out[(size_t)b * 1024 + h * 128 + d] = f2b(acc);
    }
}

// Row LayerNorm over D=1024, bf16 in -> bf16 out. 128 thr/row (2 waves).
__global__ __launch_bounds__(128) void ln_rows_b(const short* __restrict__ X,
                                                 short* __restrict__ Y,
                                                 const float* __restrict__ g,
                                                 const float* __restrict__ bt)
{
    const int row = blockIdx.x, tid = threadIdx.x;
    s16x8 v = *(const s16x8*)(X + (size_t)row * 1024 + tid * 8);
    float f[8];
    float s = 0.f, q = 0.f;
#pragma unroll
    for (int j = 0; j < 8; j++) { f[j] = b2f(v[j]); s += f[j]; q += f[j] * f[j]; }
#pragma unroll
    for (int o = 1; o < 64; o <<= 1) { s += __shfl_xor(s, o); q += __shfl_xor(q, o); }
    __shared__ float ls[2], lq[2];
    if ((tid & 63) == 0) { ls[tid >> 6] = s; lq[tid >> 6] = q; }
    __syncthreads();
    s = ls[0] + ls[1];
    q = lq[0] + lq[1];
    const float mean = s * 0.0009765625f;
    const float var  = q * 0.0009765625f - mean * mean;
    const float rs = rsqrtf(var + 1e-5f);
    s16x8 ov;
#pragma unroll
    for (int j = 0; j < 8; j++) {
        int c = tid * 8 + j;
        ov[j] = f2b((f[j] - mean) * rs * g[c] + bt[c]);
    }
    *(s16x8*)(Y + (size_t)row * 1024 + tid * 8) = ov;
}

// f32 -> bf16 flat convert (n multiple of 8)
__global__ __launch_bounds__(256) void convf2b(const float* __restrict__ s,
                                               short* __restrict__ d, int n)
{
    int i = (blockIdx.x * 256 + threadIdx.x) * 8;
    if (i < n) {
        float4 a = *(const float4*)(s + i);
        float4 b = *(const float4*)(s + i + 4);
        s16x8 o;
        o[0] = f2b(a.x); o[1] = f2b(a.y); o[2] = f2b(a.z); o[3] = f2b(a.w);
        o[4] = f2b(b.x); o[5] = f2b(b.y); o[6] = f2b(b.z); o[7] = f2b(b.w);
        *(s16x8*)(d + i) = o;
    }
}

// batched f32 [R,C] -> bf16 [C,R] transpose-convert; blockIdx.z = matrix idx
__global__ __launch_bounds__(256) void transpose_conv_b(const float* __restrict__ src0,
                                                        short* __restrict__ dst0,
                                                        int R, int C)
{
    const float* src = src0 + (size_t)blockIdx.z * R * C;
    short* dst = dst0 + (size_t)blockIdx.z * R * C;
    __shared__ float t[32][33];
    int c0 = blockIdx.x * 32, r0 = blockIdx.y * 32;
    int tx = threadIdx.x & 31, ty = threadIdx.x >> 5;
#pragma unroll
    for (int i = 0; i < 32; i += 8) t[ty + i][tx] = src[(size_t)(r0 + ty + i) * C + c0 + tx];
    __syncthreads();
#pragma unroll
    for (int i = 0; i < 32; i += 8) dst[(size_t)(c0 + ty + i) * R + r0 + tx] = f2b(t[tx][ty + i]);
}

// pad rows to 128 (cols=1024), zero-fill beyond src_rows
__global__ __launch_bounds__(256) void pad_conv(const float* __restrict__ s,
                                                short* __restrict__ d, int src_rows)
{
    int i = blockIdx.x * 256 + threadIdx.x;
    int r = i >> 10;
    d[i] = (r < src_rows) ? f2b(s[i]) : (short)0;
}

// positional encoding table [32,1024]
__global__ __launch_bounds__(256) void pe_build(float* __restrict__ pe)
{
    int i = blockIdx.x * 256 + threadIdx.x;
    int t = i >> 10, d = i & 1023;
    int de = d & ~1;
    float ang = (float)t * expf((float)de * (-9.2103403719761836f / 1024.f));
    pe[i] = (d & 1) ? cosf(ang) : sinf(ang);
}

// gather last decode position: xlast[b] = x[b*32+31]
__global__ __launch_bounds__(256) void gather_last(const short* __restrict__ x,
                                                   short* __restrict__ xlast)
{
    int i = blockIdx.x * 256 + threadIdx.x;
    int b = i >> 10, d = i & 1023;
    xlast[i] = x[((size_t)(b * 32 + 31) << 10) + d];
}

// Final routed heads -> nll[b]. One wave per batch element.
__global__ __launch_bounds__(64) void head_final(
    const float* __restrict__ logits_a,
    const float* __restrict__ enc_col_f, const short* __restrict__ yc,
    const float* __restrict__ enc_tab_f, const short* __restrict__ yt,
    const float* __restrict__ outf,
    const float* __restrict__ col_b, const float* __restrict__ tab_b,
    const int* __restrict__ view, const int* __restrict__ ga,
    const int* __restrict__ gc, const int* __restrict__ gt,
    float* __restrict__ nll)
{
    const int b = blockIdx.x, lane = threadIdx.x;
    const int vt = view[b];
    if (vt == 0) {
        float x = logits_a[(size_t)b * 128 + lane];
        float mx = x;
#pragma unroll
        for (int o = 1; o < 64; o <<= 1) mx = fmaxf(mx, __shfl_xor(mx, o));
        float sum = __expf(x - mx);
#pragma unroll
        for (int o = 1; o < 64; o <<= 1) sum += __shfl_xor(sum, o);
        float lse = mx + logf(sum);
        float gl = __shfl(x, ga[b]);
        if (lane == 0) nll[b] = lse - gl;
    } else {
        const int nit = (vt == 1) ? 32 : 16;
        const float* enc = (vt == 1) ? (enc_col_f + (size_t)b * 32 * 1024)
                                     : (enc_tab_f + (size_t)b * 16 * 1024);
        const short* y   = (vt == 1) ? (yc + (size_t)b * 1024) : (yt + (size_t)b * 1024);
        const float* bb  = (vt == 1) ? col_b : tab_b;
        float bc = 0.f;
        for (int i = lane; i < 1024; i += 64) bc += bb[i] * outf[(size_t)b * 1024 + i];
#pragma unroll
        for (int o = 1; o < 64; o <<= 1) bc += __shfl_xor(bc, o);
        float logit = -1e30f;
        if (lane < nit) {
            float s = bc;
            const float* er = enc + (size_t)lane * 1024;
            for (int d8 = 0; d8 < 128; d8++) {
                s16x8 yv = *(const s16x8*)(y + d8 * 8);
                float4 e0 = *(const float4*)(er + d8 * 8);
                float4 e1 = *(const float4*)(er + d8 * 8 + 4);
                s += e0.x * b2f(yv[0]) + e0.y * b2f(yv[1]) + e0.z * b2f(yv[2]) + e0.w * b2f(yv[3])
                   + e1.x * b2f(yv[4]) + e1.y * b2f(yv[5]) + e1.z * b2f(yv[6]) + e1.w * b2f(yv[7]);
            }
            logit = s;
        }
        float mx = logit;
#pragma unroll
        for (int o = 1; o < 64; o <<= 1) mx = fmaxf(mx, __shfl_xor(mx, o));
        float sum = (lane < nit) ? __expf(logit - mx) : 0.f;
#pragma unroll
        for (int o = 1; o < 64; o <<= 1) sum += __shfl_xor(sum, o);
        float lse = mx + logf(sum);
        int g = (vt == 1) ? gc[b] : gt[b];
        float gl = __shfl(logit, g);
        if (lane == 0) nll[b] = lse - gl;
    }
}

// ---------------------------------------------------------------------------
extern "C" void kernel_launch(void* const* d_in, const int* in_sizes, int n_in,
                              void* d_out, int out_size, void* d_ws, size_t ws_size,
                              hipStream_t stream)
{
    const float* pa_f     = (const float*)d_in[0];
    const float* src_f    = (const float*)d_in[1];
    const float* colenc_f = (const float*)d_in[2];
    const float* tabenc_f = (const float*)d_in[3];
    const int*   src_mask = (const int*)d_in[4];
    const int*   sym_ids  = (const int*)d_in[5];
    const int*   view     = (const int*)d_in[6];
    const int*   gold_a   = (const int*)d_in[7];
    const int*   gold_c   = (const int*)d_in[8];
    const int*   gold_t   = (const int*)d_in[9];
    const float* sym_emb  = (const float*)d_in[10];
    const float* act_emb  = (const float*)d_in[11];
    const float* Aaff_w   = (const float*)d_in[12];
    const float* Aaff_b   = (const float*)d_in[13];
    const float* Saff_w   = (const float*)d_in[14];
    const float* Saff_b   = (const float*)d_in[15];
    const float* Caff_w   = (const float*)d_in[16];
    const float* Caff_b   = (const float*)d_in[17];
    const float* Taff_w   = (const float*)d_in[18];
    const float* Taff_b   = (const float*)d_in[19];
    const float* tgt_w    = (const float*)d_in[20];
    const float* tgt_b    = (const float*)d_in[21];
    const float* outw     = (const float*)d_in[22];
    const float* outbias  = (const float*)d_in[23];
    const float* self_w   = (const float*)d_in[24];
    const float* self_b   = (const float*)d_in[25];
    const float* cross_w  = (const float*)d_in[26];
    const float* cross_b  = (const float*)d_in[27];
    const float* f1w      = (const float*)d_in[28];
    const float* f1b      = (const float*)d_in[29];
    const float* f2w      = (const float*)d_in[30];
    const float* f2bb     = (const float*)d_in[31];
    const float* lng      = (const float*)d_in[32];
    const float* lnbt     = (const float*)d_in[33];
    float* nll = (float*)d_out;

    char* ws = (char*)d_ws;
    size_t off = 0;
    auto alloc = [&](size_t bytes) -> char* {
        off = (off + 255) & ~(size_t)255;
        char* p = ws + off; off += bytes; return p;
    };

    const size_t MB1 = (size_t)1024 * 1024;
    short* WAaff  = (short*)alloc(MB1 * 2);
    short* WSaff  = (short*)alloc(MB1 * 2);
    short* Wtop   = (short*)alloc(MB1 * 2);
    short* Wbot   = (short*)alloc(MB1 * 2);
    short* Wout   = (short*)alloc(MB1 * 2);
    short* Wcol   = (short*)alloc(MB1 * 2);
    short* Wtab   = (short*)alloc(MB1 * 2);
    short* Aaffrm = (short*)alloc(MB1 * 2);
    short* Wcomb  = (short*)alloc(MB1 * 2);
    float* cbias  = (float*)alloc(1024 * 4);
    short* Wself  = (short*)alloc(12 * MB1 * 2);
    short* Wcross = (short*)alloc(12 * MB1 * 2);
    short* Wf1a   = (short*)alloc(3 * 2 * MB1 * 2);
    short* Wf2a   = (short*)alloc(3 * 2 * MB1 * 2);

    short* src_bf   = (short*)alloc((size_t)16384 * 1024 * 2);
    short* sym_pad  = (short*)alloc((size_t)128 * 1024 * 2);
    short* act_pad  = (short*)alloc((size_t)128 * 1024 * 2);
    short* sa_out   = (short*)alloc((size_t)128 * 1024 * 2);
    float* sym2     = (float*)alloc((size_t)128 * 1024 * 4);
    float* pe       = (float*)alloc((size_t)32 * 1024 * 4);
    short* attn     = (short*)alloc((size_t)8192 * 1024 * 2);
    short* x_bf     = (short*)alloc((size_t)8192 * 1024 * 2);
    short* tmpb     = (short*)alloc((size_t)8192 * 1024 * 2);
    short* arena    = (short*)alloc((size_t)16384 * 2048 * 2);
    short* xlast    = (short*)alloc((size_t)256 * 1024 * 2);
    float* outf     = (float*)alloc((size_t)256 * 1024 * 4);
    short* outb16   = (short*)alloc((size_t)256 * 1024 * 2);
    short* srca     = (short*)alloc((size_t)128 * 1024 * 2);
    float* logits_a = (float*)alloc((size_t)256 * 128 * 4);
    short* ycb      = (short*)alloc((size_t)256 * 1024 * 2);
    short* ytb      = (short*)alloc((size_t)256 * 1024 * 2);
    short* xq31     = (short*)alloc((size_t)256 * 1024 * 2);
    short* x256a    = (short*)alloc((size_t)256 * 1024 * 2);
    short* x256b    = (short*)alloc((size_t)256 * 1024 * 2);
    short* q256     = (short*)alloc((size_t)256 * 1024 * 2);
    short* cq256    = (short*)alloc((size_t)256 * 1024 * 2);
    short* o256     = (short*)alloc((size_t)256 * 1024 * 2);
    short* h256     = (short*)alloc((size_t)256 * 2048 * 2);
    short* tmpb256  = (short*)alloc((size_t)256 * 1024 * 2);

    short* pa_bf = tmpb;   // alias: dead before tmpb first written (layer0 o-proj)
    short* cq    = tmpb;   // alias: live only between LN1 and cross attn

    const dim3 BLK(256);
    auto conv = [&](const float* s, short* d, size_t n) {
        convf2b<<<dim3((unsigned)(n / 8 / 256)), BLK, 0, stream>>>(s, d, (int)n);
    };
    auto trans = [&](const float* s, short* d, int R, int C, int nm) {
        transpose_conv_b<<<dim3(C / 32, R / 32, nm), BLK, 0, stream>>>(s, d, R, C);
    };
    auto gh = [&](const short* A, const short* Bt, const float* bias,
                  short* Cb, const short* res,
                  const float* sy, const int* si, const float* pp,
                  int M, int N, int K, int epi) {
        gemm_hi<<<dim3((N / 128) * (M / 64)), BLK, 0, stream>>>(
            A, Bt, bias, Cb, res, sy, si, pp, M, N, K, epi);
    };
    auto gsm = [&](const short* A, const short* Bt, const float* bias,
                   float* Cf, short* Cb, const short* res,
                   int M, int N, int K, int epi) {
        gemm_bt<<<dim3(N / 128, M / 128), BLK, 0, stream>>>(
            A, Bt, bias, Cf, Cb, res, M, N, K, epi);
    };

    // ---- phase 0: conversions (batched) ----------------------------------
    pe_build<<<dim3(128), BLK, 0, stream>>>(pe);
    conv(pa_f, pa_bf, (size_t)8192 * 1024);
    conv(src_f, src_bf, (size_t)16384 * 1024);
    conv(Caff_w, Wcol, MB1);
    conv(Taff_w, Wtab, MB1);
    conv(Aaff_w, Aaffrm, MB1);
    pad_conv<<<dim3(512), BLK, 0, stream>>>(sym_emb, sym_pad, 32);
    pad_conv<<<dim3(512), BLK, 0, stream>>>(act_emb, act_pad, 64);
    trans(Aaff_w, WAaff, 1024, 1024, 1);
    trans(Saff_w, WSaff, 1024, 1024, 1);
    trans(tgt_w, Wtop, 1024, 1024, 1);
    trans(tgt_w + MB1, Wbot, 1024, 1024, 1);
    trans(outw, Wout, 1024, 1024, 1);
    trans(self_w, Wself, 1024, 1024, 12);
    trans(cross_w, Wcross, 1024, 1024, 12);
    trans(f1w, Wf1a, 1024, 2048, 3);
    trans(f2w, Wf2a, 2048, 1024, 3);

    // ---- phase 1: embeddings (fused affine∘linear) -----------------------
    gsm(Wtop, Aaffrm, nullptr, nullptr, Wcomb, nullptr, 1024, 1024, 1024, 0);
    vecmat_bias<<<dim3(4), BLK, 0, stream>>>(Aaff_b, tgt_w, tgt_b, cbias);
    gsm(sym_pad, WSaff, Saff_b, nullptr, sa_out, nullptr, 128, 1024, 1024, 0);
    gsm(sa_out, Wbot, nullptr, sym2, nullptr, nullptr, 128, 1024, 1024, 1);
    gh(pa_bf, Wcomb, cbias, x_bf, nullptr, sym2, sym_ids, pe,
       8192, 1024, 1024, 2);

    // ---- phase 2: decoder layers 0,1 (full) ------------------------------
    for (int l = 0; l < 2; l++) {
        const float* sb = self_b + (size_t)l * 4096;
        const float* cb = cross_b + (size_t)l * 4096;
        gh(x_bf, Wself + (size_t)(4 * l) * MB1, sb, arena, nullptr, nullptr, nullptr, nullptr,
           8192, 3072, 1024, 0);
        attn_self<<<dim3(2048), BLK, 0, stream>>>(arena, attn);
        gh(attn, Wself + (size_t)(4 * l + 3) * MB1, sb + 3072, tmpb, x_bf, nullptr, nullptr, nullptr,
           8192, 1024, 1024, 6);
        ln_rows_b<<<dim3(8192), dim3(128), 0, stream>>>(tmpb, x_bf,
            lng + (size_t)(l * 3 + 0) * 1024, lnbt + (size_t)(l * 3 + 0) * 1024);
        gh(x_bf, Wcross + (size_t)(4 * l) * MB1, cb, cq, nullptr, nullptr, nullptr, nullptr,
           8192, 1024, 1024, 0);
        gh(src_bf, Wcross + (size_t)(4 * l + 1) * MB1, cb + 1024, arena, nullptr, nullptr, nullptr, nullptr,
           16384, 2048, 1024, 0);
        attn_cross<<<dim3(2048), BLK, 0, stream>>>(cq, arena, src_mask, attn);
        gh(attn, Wcross + (size_t)(4 * l + 3) * MB1, cb + 3072, tmpb, x_bf, nullptr, nullptr, nullptr,
           8192, 1024, 1024, 6);
        ln_rows_b<<<dim3(8192), dim3(128), 0, stream>>>(tmpb, x_bf,
            lng + (size_t)(l * 3 + 1) * 1024, lnbt + (size_t)(l * 3 + 1) * 1024);
        gh(x_bf, Wf1a + (size_t)l * 2 * MB1, f1b + (size_t)l * 2048, arena, nullptr, nullptr, nullptr, nullptr,
           8192, 2048, 1024, 3);
        gh(arena, Wf2a + (size_t)l * 2 * MB1, f2bb + (size_t)l * 1024, tmpb, x_bf, nullptr, nullptr, nullptr,
           8192, 1024, 2048, 6);
        ln_rows_b<<<dim3(8192), dim3(128), 0, stream>>>(tmpb, x_bf,
            lng + (size_t)(l * 3 + 2) * 1024, lnbt + (size_t)(l * 3 + 2) * 1024);
    }

    // ---- layer 2: only last position matters downstream ------------------
    {
        const float* sb = self_b + (size_t)2 * 4096;
        const float* cb = cross_b + (size_t)2 * 4096;
        gather_last<<<dim3(1024), BLK, 0, stream>>>(x_bf, xq31);
        gh(x_bf, Wself + (size_t)(4 * 2 + 1) * MB1, sb + 1024, arena, nullptr, nullptr, nullptr, nullptr,
           8192, 2048, 1024, 0);   // K,V all positions
        gsm(xq31, Wself + (size_t)(4 * 2) * MB1, sb, nullptr, q256, nullptr, 256, 1024, 1024, 0);
        attn_self_last<<<dim3(512), BLK, 0, stream>>>(q256, arena, o256);
        gsm(o256, Wself + (size_t)(4 * 2 + 3) * MB1, sb + 3072, nullptr, tmpb256, xq31, 256, 1024, 1024, 6);
        ln_rows_b<<<dim3(256), dim3(128), 0, stream>>>(tmpb256, x256a,
            lng + (size_t)(2 * 3 + 0) * 1024, lnbt + (size_t)(2 * 3 + 0) * 1024);
        gsm(x256a, Wcross + (size_t)(4 * 2) * MB1, cb, nullptr, cq256, nullptr, 256, 1024, 1024, 0);
        gh(src_bf, Wcross + (size_t)(4 * 2 + 1) * MB1, cb + 1024, arena, nullptr, nullptr, nullptr, nullptr,
           16384, 2048, 1024, 0);
        attn_cross_last<<<dim3(512), BLK, 0, stream>>>(cq256, arena, src_mask, o256);
        gsm(o256, Wcross + (size_t)(4 * 2 + 3) * MB1, cb + 3072, nullptr, tmpb256, x256a, 256, 1024, 1024, 6);
        ln_rows_b<<<dim3(256), dim3(128), 0, stream>>>(tmpb256, x256b,
            lng + (size_t)(2 * 3 + 1) * 1024, lnbt + (size_t)(2 * 3 + 1) * 1024);
        gsm(x256b, Wf1a + (size_t)2 * 2 * MB1, f1b + (size_t)2 * 2048, nullptr, h256, nullptr,
            256, 2048, 1024, 3);
        gsm(h256, Wf2a + (size_t)2 * 2 * MB1, f2bb + (size_t)2 * 1024, nullptr, tmpb256, x256b,
            256, 1024, 2048, 6);
        ln_rows_b<<<dim3(256), dim3(128), 0, stream>>>(tmpb256, xlast,
            lng + (size_t)(2 * 3 + 2) * 1024, lnbt + (size_t)(2 * 3 + 2) * 1024);
    }

    // ---- phase 3: heads --------------------------------------------------
    gsm(xlast, Wout, outbias, outf, outb16, nullptr, 256, 1024, 1024, 5);
    gsm(act_pad, WAaff, Aaff_b, nullptr, srca, nullptr, 128, 1024, 1024, 0);
    gsm(outb16, srca, nullptr, logits_a, nullptr, nullptr, 256, 128, 1024, 1);
    gsm(outb16, Wcol, nullptr, nullptr, ycb, nullptr, 256, 1024, 1024, 0);
    gsm(outb16, Wtab, nullptr, nullptr, ytb, nullptr, 256, 1024, 1024, 0);
    head_final<<<dim3(256), dim3(64), 0, stream>>>(
        logits_a, colenc_f, ycb, tabenc_f, ytb, outf,
        Caff_b, Taff_b, view, gold_a, gold_c, gold_t, nll);
}